// Round 5
// baseline (703.921 us; speedup 1.0000x reference)
//
#include <hip/hip_runtime.h>
#include <math.h>

// Problem dims (fixed by reference)
#define CC 4
#define FE 32
#define HH 64
#define EBS 256

typedef __attribute__((ext_vector_type(8))) short bf16x8;
typedef __attribute__((ext_vector_type(4))) float f32x4;

// bf16 round-to-nearest-even pack
__device__ inline unsigned short f2bf(float f) {
    unsigned u = __float_as_uint(f);
    u += 0x7fffu + ((u >> 16) & 1u);
    return (unsigned short)(u >> 16);
}
__device__ inline float bf2f(unsigned short b) {
    return __uint_as_float(((unsigned)b) << 16);
}

// ---------------------------------------------------------------------------
// Kernel A: x[n,c,j] = sum_{i,a} node_input[n,c,i] * node_attr[n,a] * W_lin1[i,a,j]
// ---------------------------------------------------------------------------
__global__ __launch_bounds__(256) void k_lin1(
    const float* __restrict__ node_input, const float* __restrict__ node_attr,
    const float* __restrict__ W_lin1, float* __restrict__ xout, int n_nc)
{
    int t = blockIdx.x * 256 + threadIdx.x;
    if (t >= n_nc) return;
    int n = t >> 2;
    float attr[16];
    #pragma unroll
    for (int a = 0; a < 16; ++a) attr[a] = node_attr[(size_t)n * 16 + a];
    float xi[8];
    #pragma unroll
    for (int i = 0; i < 8; ++i) xi[i] = node_input[(size_t)t * 8 + i];
    float xo[8] = {0.f, 0.f, 0.f, 0.f, 0.f, 0.f, 0.f, 0.f};
    #pragma unroll
    for (int i = 0; i < 8; ++i) {
        #pragma unroll
        for (int a = 0; a < 16; ++a) {
            float f = xi[i] * attr[a];
            #pragma unroll
            for (int j = 0; j < 8; ++j)
                xo[j] += f * W_lin1[(i * 16 + a) * 8 + j];
        }
    }
    #pragma unroll
    for (int j = 0; j < 8; ++j) xout[(size_t)t * 8 + j] = xo[j];
}

// ---------------------------------------------------------------------------
// CSR build over edge_dst
// ---------------------------------------------------------------------------
__global__ __launch_bounds__(256) void k_hist(
    const int* __restrict__ edge_dst, int* __restrict__ counts, int E)
{
    int e = blockIdx.x * 256 + threadIdx.x;
    if (e < E) atomicAdd(&counts[edge_dst[e]], 1);
}

// single-block shfl-based scan (16 waves of 64)
__global__ __launch_bounds__(1024) void k_scan(
    const int* __restrict__ counts, int* __restrict__ offsets,
    int* __restrict__ cursor, int N)
{
    __shared__ int wsum[16];
    __shared__ int wpre[16];
    __shared__ int s_tot;
    __shared__ int s_carry;
    int tid = threadIdx.x, wid = tid >> 6, lane = tid & 63;
    if (tid == 0) s_carry = 0;
    __syncthreads();
    for (int base = 0; base < N; base += 1024) {
        int idx = base + tid;
        int v = (idx < N) ? counts[idx] : 0;
        int x = v;
        #pragma unroll
        for (int s = 1; s < 64; s <<= 1) {
            int y = __shfl_up(x, s);
            if (lane >= s) x += y;
        }
        if (lane == 63) wsum[wid] = x;
        __syncthreads();
        if (wid == 0) {
            int wv = (lane < 16) ? wsum[lane] : 0;
            int wx = wv;
            #pragma unroll
            for (int s = 1; s < 16; s <<= 1) {
                int y = __shfl_up(wx, s);
                if (lane >= s) wx += y;
            }
            if (lane < 16) wpre[lane] = wx - wv;
            if (lane == 15) s_tot = wx;
        }
        __syncthreads();
        if (idx < N) {
            int excl = s_carry + wpre[wid] + (x - v);
            offsets[idx] = excl;
            cursor[idx] = excl;
        }
        __syncthreads();
        if (tid == 0) s_carry += s_tot;
    }
}

// fill permutation; also gather srcs into perm order
__global__ __launch_bounds__(256) void k_fill(
    const int* __restrict__ edge_dst, const int* __restrict__ edge_src,
    int* __restrict__ cursor, int* __restrict__ perm, int* __restrict__ srcs, int E)
{
    int e = blockIdx.x * 256 + threadIdx.x;
    if (e < E) {
        int pos = atomicAdd(&cursor[edge_dst[e]], 1);
        perm[pos] = e;
        srcs[pos] = edge_src[e];
    }
}

// ---------------------------------------------------------------------------
// Pack W2 into MFMA B-fragment order (bf16).
// ---------------------------------------------------------------------------
__global__ __launch_bounds__(256) void k_prep_bfrag(
    const float* __restrict__ fc_w2, unsigned short* __restrict__ Bfrag)
{
    int t = blockIdx.x * 256 + threadIdx.x;
    if (t >= 512 * 64) return;
    int kappa = t >> 6, nu = t & 63;
    int k = kappa >> 3, i = kappa & 7, d = nu >> 3, o = nu & 7;
    float val = fc_w2[(size_t)k * 512 + d * 64 + i * 8 + o];
    int kk = kappa >> 5;
    int lane = ((kappa >> 3) & 3) * 16 + (nu & 15);
    int ct = nu >> 4;
    int j = kappa & 7;
    Bfrag[(size_t)((kk * 4 + ct) * 64 + lane) * 8 + j] = f2bf(val);
}

// ---------------------------------------------------------------------------
// H build: H[p, k] = silu(ef[perm[p],:] . W1[:,k] + b1[k]) as bf16, perm order.
// ---------------------------------------------------------------------------
__global__ __launch_bounds__(256) void k_hsilu(
    const float* __restrict__ edge_features,
    const float* __restrict__ fc_w1, const float* __restrict__ fc_b1,
    const int* __restrict__ perm,
    unsigned short* __restrict__ H, int E)
{
    __shared__ float w1lds[FE * HH];
    __shared__ float b1lds[HH];
    int tid = threadIdx.x;
    #pragma unroll
    for (int it = 0; it < (FE * HH) / 256; ++it)
        w1lds[it * 256 + tid] = fc_w1[it * 256 + tid];
    if (tid < HH) b1lds[tid] = fc_b1[tid];
    __syncthreads();

    int p = blockIdx.x * 256 + tid;
    if (p >= E) return;
    int e = perm[p];

    float efv[FE];
    const float4* efp = reinterpret_cast<const float4*>(edge_features + (size_t)e * FE);
    #pragma unroll
    for (int q = 0; q < FE / 4; ++q) {
        float4 v = efp[q];
        efv[q * 4 + 0] = v.x; efv[q * 4 + 1] = v.y;
        efv[q * 4 + 2] = v.z; efv[q * 4 + 3] = v.w;
    }
    float h[HH];
    #pragma unroll
    for (int k = 0; k < HH; ++k) h[k] = b1lds[k];
    #pragma unroll
    for (int f = 0; f < FE; ++f) {
        float ev = efv[f];
        const float4* wp = reinterpret_cast<const float4*>(&w1lds[f * HH]);
        #pragma unroll
        for (int q = 0; q < HH / 4; ++q) {
            float4 w = wp[q];
            h[q * 4 + 0] += ev * w.x;
            h[q * 4 + 1] += ev * w.y;
            h[q * 4 + 2] += ev * w.z;
            h[q * 4 + 3] += ev * w.w;
        }
    }
    unsigned short* Hrow = H + (size_t)p * HH;
    #pragma unroll
    for (int q = 0; q < 8; ++q) {
        float s0 = h[q * 8 + 0], s1 = h[q * 8 + 1], s2 = h[q * 8 + 2], s3 = h[q * 8 + 3];
        float s4 = h[q * 8 + 4], s5 = h[q * 8 + 5], s6 = h[q * 8 + 6], s7 = h[q * 8 + 7];
        s0 /= (1.f + __expf(-s0)); s1 /= (1.f + __expf(-s1));
        s2 /= (1.f + __expf(-s2)); s3 /= (1.f + __expf(-s3));
        s4 /= (1.f + __expf(-s4)); s5 /= (1.f + __expf(-s5));
        s6 /= (1.f + __expf(-s6)); s7 /= (1.f + __expf(-s7));
        uint4 pk;
        pk.x = (unsigned)f2bf(s0) | ((unsigned)f2bf(s1) << 16);
        pk.y = (unsigned)f2bf(s2) | ((unsigned)f2bf(s3) << 16);
        pk.z = (unsigned)f2bf(s4) | ((unsigned)f2bf(s5) << 16);
        pk.w = (unsigned)f2bf(s6) | ((unsigned)f2bf(s7) << 16);
        reinterpret_cast<uint4*>(Hrow)[q] = pk;
    }
}

// ---------------------------------------------------------------------------
// Z build: one wave per node. lane k owns h[e,k].
// ---------------------------------------------------------------------------
__global__ __launch_bounds__(256) void k_zbuild(
    const unsigned short* __restrict__ H, const int* __restrict__ srcs,
    const int* __restrict__ offsets, const int* __restrict__ counts,
    const float* __restrict__ xin,
    unsigned short* __restrict__ Z, float* __restrict__ xsum,
    int n0, int nNodes)
{
    int node_l = blockIdx.x * 4 + (threadIdx.x >> 6);
    int lane = threadIdx.x & 63;
    if (node_l >= nNodes) return;
    int node = n0 + node_l;
    int off = offsets[node], cnt = counts[node];

    float z[CC][8];
    #pragma unroll
    for (int c = 0; c < CC; ++c)
        #pragma unroll
        for (int i = 0; i < 8; ++i) z[c][i] = 0.f;
    float xsown = 0.f;

    for (int base = 0; base < cnt; base += 64) {
        int m = (cnt - base < 64) ? (cnt - base) : 64;
        int sj = (lane < m) ? srcs[off + base + lane] : 0;
        #pragma unroll 2
        for (int j = 0; j < m; ++j) {
            int src = __shfl(sj, j);
            float hk = bf2f(H[(size_t)(off + base + j) * HH + lane]);
            const float4* xp = reinterpret_cast<const float4*>(xin + (size_t)src * 32);
            float xs[32];
            #pragma unroll
            for (int q = 0; q < 8; ++q) {
                float4 v = xp[q];
                xs[q * 4 + 0] = v.x; xs[q * 4 + 1] = v.y;
                xs[q * 4 + 2] = v.z; xs[q * 4 + 3] = v.w;
            }
            #pragma unroll
            for (int c = 0; c < CC; ++c)
                #pragma unroll
                for (int i = 0; i < 8; ++i)
                    z[c][i] += hk * xs[c * 8 + i];
            xsown += xin[(size_t)src * 32 + (lane & 31)];
        }
    }

    #pragma unroll
    for (int c = 0; c < CC; ++c) {
        uint4 pk;
        pk.x = (unsigned)f2bf(z[c][0]) | ((unsigned)f2bf(z[c][1]) << 16);
        pk.y = (unsigned)f2bf(z[c][2]) | ((unsigned)f2bf(z[c][3]) << 16);
        pk.z = (unsigned)f2bf(z[c][4]) | ((unsigned)f2bf(z[c][5]) << 16);
        pk.w = (unsigned)f2bf(z[c][6]) | ((unsigned)f2bf(z[c][7]) << 16);
        reinterpret_cast<uint4*>(Z)[(size_t)(node_l * 4 + c) * 64 + lane] = pk;
    }
    if (lane < 32) xsum[(size_t)node * 32 + lane] = xsown;
}

// ---------------------------------------------------------------------------
// GEMM: agg[M,64] = Z[M,512] @ W2r[512,64], bf16 MFMA 16x16x32, fp32 out.
// ---------------------------------------------------------------------------
__global__ __launch_bounds__(256) void k_gemm(
    const unsigned short* __restrict__ Z, const unsigned short* __restrict__ Bfrag,
    float* __restrict__ out, int row_base, int M)
{
    __shared__ short blds[32768];
    int tid = threadIdx.x;
    #pragma unroll
    for (int it = 0; it < 16; ++it) {
        int idx = it * 256 + tid;
        reinterpret_cast<uint4*>(blds)[idx] = reinterpret_cast<const uint4*>(Bfrag)[idx];
    }
    __syncthreads();

    int w = tid >> 6, l = tid & 63;
    int rbase = blockIdx.x * 64 + w * 16;
    int arow = rbase + (l & 15);
    if (arow >= M) arow = M - 1;

    f32x4 acc[4];
    #pragma unroll
    for (int ct = 0; ct < 4; ++ct) acc[ct] = (f32x4){0.f, 0.f, 0.f, 0.f};

    #pragma unroll
    for (int kk = 0; kk < 16; ++kk) {
        uint4 av = reinterpret_cast<const uint4*>(Z)[(size_t)arow * 64 + kk * 4 + (l >> 4)];
        bf16x8 a = *reinterpret_cast<bf16x8*>(&av);
        #pragma unroll
        for (int ct = 0; ct < 4; ++ct) {
            bf16x8 b = *reinterpret_cast<const bf16x8*>(&blds[(size_t)((kk * 4 + ct) * 64 + l) * 8]);
            acc[ct] = __builtin_amdgcn_mfma_f32_16x16x32_bf16(a, b, acc[ct], 0, 0, 0);
        }
    }

    #pragma unroll
    for (int ct = 0; ct < 4; ++ct) {
        #pragma unroll
        for (int v = 0; v < 4; ++v) {
            int r = rbase + (l >> 4) * 4 + v;
            if (r < M)
                out[(size_t)(row_base + r) * 64 + ct * 16 + (l & 15)] = acc[ct][v];
        }
    }
}

// ---------------------------------------------------------------------------
// Fallback edge kernel (global atomics) — only if ws too small.
// ---------------------------------------------------------------------------
__global__ __launch_bounds__(EBS) void k_edge_atomic(
    const float* __restrict__ edge_features,
    const float* __restrict__ fc_w1, const float* __restrict__ fc_b1,
    const float* __restrict__ fc_w2, const float* __restrict__ fc_b2,
    const int* __restrict__ edge_src, const int* __restrict__ edge_dst,
    const float* __restrict__ xin, float* __restrict__ agg, int E)
{
    __shared__ float hlds[HH * EBS];
    int e = blockIdx.x * EBS + threadIdx.x;
    if (e >= E) return;
    float h[HH];
    #pragma unroll
    for (int k = 0; k < HH; ++k) h[k] = fc_b1[k];
    const float4* efp = reinterpret_cast<const float4*>(edge_features + (size_t)e * FE);
    #pragma unroll
    for (int fq = 0; fq < FE / 4; ++fq) {
        float4 efv = efp[fq];
        float ev[4] = {efv.x, efv.y, efv.z, efv.w};
        #pragma unroll
        for (int fs = 0; fs < 4; ++fs) {
            float evv = ev[fs];
            const float4* w1p = reinterpret_cast<const float4*>(fc_w1 + (fq * 4 + fs) * HH);
            #pragma unroll
            for (int q = 0; q < HH / 4; ++q) {
                float4 w = w1p[q];
                h[q * 4 + 0] += evv * w.x;
                h[q * 4 + 1] += evv * w.y;
                h[q * 4 + 2] += evv * w.z;
                h[q * 4 + 3] += evv * w.w;
            }
        }
    }
    #pragma unroll
    for (int k = 0; k < HH; ++k) {
        float v = h[k];
        hlds[k * EBS + threadIdx.x] = v / (1.f + __expf(-v));
    }
    int src = edge_src[e], dst = edge_dst[e];
    float xs[32];
    const float4* xp = reinterpret_cast<const float4*>(xin + (size_t)src * 32);
    #pragma unroll
    for (int q = 0; q < 8; ++q) {
        float4 v = xp[q];
        xs[q * 4 + 0] = v.x; xs[q * 4 + 1] = v.y;
        xs[q * 4 + 2] = v.z; xs[q * 4 + 3] = v.w;
    }
    float* outp = agg + (size_t)dst * 256;
    #pragma unroll 1
    for (int d = 0; d < 8; ++d) {
        float t[64];
        const float4* b2p = reinterpret_cast<const float4*>(fc_b2 + d * 64);
        #pragma unroll
        for (int q = 0; q < 16; ++q) {
            float4 v = b2p[q];
            t[q * 4 + 0] = v.x; t[q * 4 + 1] = v.y;
            t[q * 4 + 2] = v.z; t[q * 4 + 3] = v.w;
        }
        for (int k = 0; k < HH; ++k) {
            float hv = hlds[k * EBS + threadIdx.x];
            const float4* wp = reinterpret_cast<const float4*>(fc_w2 + (size_t)k * 512 + d * 64);
            #pragma unroll
            for (int q = 0; q < 16; ++q) {
                float4 w = wp[q];
                t[q * 4 + 0] += hv * w.x;
                t[q * 4 + 1] += hv * w.y;
                t[q * 4 + 2] += hv * w.z;
                t[q * 4 + 3] += hv * w.w;
            }
        }
        #pragma unroll
        for (int c = 0; c < CC; ++c) {
            #pragma unroll
            for (int o = 0; o < 8; ++o) {
                float acc = 0.f;
                #pragma unroll
                for (int i = 0; i < 8; ++i) acc += xs[c * 8 + i] * t[i * 8 + o];
                atomicAdd(outp + c * 64 + d * 8 + o, acc);
            }
        }
    }
}

// ---------------------------------------------------------------------------
// Kernel C (rewritten): LDS-staged weights + cooperative per-node w2n.
// Thread t=(n,c). 4 threads of a node each build 2 o-rows of w2n in LDS.
// ---------------------------------------------------------------------------
__global__ __launch_bounds__(256) void k_node_out(
    const float* __restrict__ node_input, const float* __restrict__ node_attr,
    const float* __restrict__ W_sc, const float* __restrict__ W_lin2,
    const float* __restrict__ fc_b2, const float* __restrict__ xsum,
    float* __restrict__ out, int n_nc, int use_xsum)
{
    const float c_s = 0.3826834323650898f;
    const float c_x_scaled = 0.9238795325112867f * 0.35355339059327373f;
    __shared__ float wsc_l[1024];
    __shared__ float wl2_l[1024];
    __shared__ float b2_l[512];
    __shared__ float w2n_l[64 * 68];   // per-node 8x8 w2n, stride 68 to spread banks

    int tid = threadIdx.x;
    #pragma unroll
    for (int it = 0; it < 4; ++it) wsc_l[it * 256 + tid] = W_sc[it * 256 + tid];
    #pragma unroll
    for (int it = 0; it < 4; ++it) wl2_l[it * 256 + tid] = W_lin2[it * 256 + tid];
    #pragma unroll
    for (int it = 0; it < 2; ++it) b2_l[it * 256 + tid] = fc_b2[it * 256 + tid];
    __syncthreads();

    int t0 = blockIdx.x * 256 + tid;
    bool active = (t0 < n_nc);
    int t = active ? t0 : (n_nc - 1);   // clamp loads; guard stores
    int n = t >> 2;
    int cw = tid & 3;                    // c (aligned with nl groups of 4)
    int nl = tid >> 2;

    float attr[16];
    #pragma unroll
    for (int a = 0; a < 16; ++a) attr[a] = node_attr[(size_t)n * 16 + a];

    // cooperative w2n: this thread builds o = cw*2, cw*2+1 (rows of 8)
    #pragma unroll
    for (int oo = 0; oo < 2; ++oo) {
        int o = cw * 2 + oo;
        float acc[8] = {0.f, 0.f, 0.f, 0.f, 0.f, 0.f, 0.f, 0.f};
        #pragma unroll
        for (int a = 0; a < 16; ++a) {
            float fa = attr[a];
            #pragma unroll
            for (int p = 0; p < 8; ++p)
                acc[p] += fa * wl2_l[(o * 16 + a) * 8 + p];
        }
        #pragma unroll
        for (int p = 0; p < 8; ++p)
            w2n_l[nl * 68 + o * 8 + p] = acc[p];
    }
    __syncthreads();

    // s[o] (genuinely per (n,c))
    float s[8] = {0.f, 0.f, 0.f, 0.f, 0.f, 0.f, 0.f, 0.f};
    #pragma unroll
    for (int i = 0; i < 8; ++i) {
        float vi = node_input[(size_t)t * 8 + i];
        #pragma unroll
        for (int a = 0; a < 16; ++a) {
            float f = vi * attr[a];
            #pragma unroll
            for (int o = 0; o < 8; ++o)
                s[o] += f * wsc_l[(i * 16 + a) * 8 + o];
        }
    }

    float xbar[8];
    #pragma unroll
    for (int i = 0; i < 8; ++i)
        xbar[i] = use_xsum ? xsum[(size_t)n * 32 + cw * 8 + i] : 0.f;

    float* rowp = out + (size_t)t * 64;
    const float* w2row = &w2n_l[nl * 68];
    #pragma unroll 1
    for (int d = 0; d < 8; ++d) {
        float4 v0 = *reinterpret_cast<const float4*>(rowp + d * 8);
        float4 v1 = *reinterpret_cast<const float4*>(rowp + d * 8 + 4);
        float aggv[8] = {v0.x, v0.y, v0.z, v0.w, v1.x, v1.y, v1.z, v1.w};
        if (use_xsum) {
            #pragma unroll
            for (int i = 0; i < 8; ++i) {
                float xb = xbar[i];
                #pragma unroll
                for (int o = 0; o < 8; ++o)
                    aggv[o] += xb * b2_l[d * 64 + i * 8 + o];
            }
        }
        float res[8] = {0.f, 0.f, 0.f, 0.f, 0.f, 0.f, 0.f, 0.f};
        #pragma unroll
        for (int o = 0; o < 8; ++o) {
            float av = aggv[o];
            #pragma unroll
            for (int p = 0; p < 8; ++p)
                res[p] += av * w2row[o * 8 + p];
        }
        if (active) {
            float4 r0, r1;
            r0.x = c_s * s[0] + c_x_scaled * res[0];
            r0.y = c_s * s[1] + c_x_scaled * res[1];
            r0.z = c_s * s[2] + c_x_scaled * res[2];
            r0.w = c_s * s[3] + c_x_scaled * res[3];
            r1.x = c_s * s[4] + c_x_scaled * res[4];
            r1.y = c_s * s[5] + c_x_scaled * res[5];
            r1.z = c_s * s[6] + c_x_scaled * res[6];
            r1.w = c_s * s[7] + c_x_scaled * res[7];
            *reinterpret_cast<float4*>(rowp + d * 8) = r0;
            *reinterpret_cast<float4*>(rowp + d * 8 + 4) = r1;
        }
    }
}

// ---------------------------------------------------------------------------
extern "C" void kernel_launch(void* const* d_in, const int* in_sizes, int n_in,
                              void* d_out, int out_size, void* d_ws, size_t ws_size,
                              hipStream_t stream)
{
    const float* node_input    = (const float*)d_in[0];
    const float* node_attr     = (const float*)d_in[1];
    const float* edge_features = (const float*)d_in[2];
    const float* W_sc          = (const float*)d_in[3];
    const float* W_lin1        = (const float*)d_in[4];
    const float* W_lin2        = (const float*)d_in[5];
    const float* fc_w1         = (const float*)d_in[6];
    const float* fc_b1         = (const float*)d_in[7];
    const float* fc_w2         = (const float*)d_in[8];
    const float* fc_b2         = (const float*)d_in[9];
    const int*   edge_src      = (const int*)d_in[10];
    const int*   edge_dst      = (const int*)d_in[11];

    const int N = in_sizes[1] / 16;
    const int E = in_sizes[10];
    const int n_nc = N * CC;

    char* ws = (char*)d_ws;
    size_t off = 0;
    auto take = [&](size_t bytes) { char* p = ws + off; off += (bytes + 15) & ~(size_t)15; return p; };
    float* xbuf            = (float*)take((size_t)N * 32 * sizeof(float));
    int*   counts          = (int*)take((size_t)N * sizeof(int));
    int*   offsets         = (int*)take((size_t)N * sizeof(int));
    int*   cursor          = (int*)take((size_t)N * sizeof(int));
    int*   perm            = (int*)take((size_t)E * sizeof(int));
    int*   srcs            = (int*)take((size_t)E * sizeof(int));
    float* xsum            = (float*)take((size_t)N * 32 * sizeof(float));
    unsigned short* Bfrag  = (unsigned short*)take((size_t)512 * 64 * sizeof(unsigned short));
    unsigned short* Hbuf   = (unsigned short*)take((size_t)E * HH * sizeof(unsigned short));
    size_t fixed_off = off;
    unsigned short* Zbuf   = (unsigned short*)(ws + fixed_off);

    long long avail = (long long)ws_size - (long long)fixed_off;
    int npp = (avail > 0) ? (int)(avail / 4096) : 0;   // 4 rows * 512 cols * 2B per node
    bool fast = (npp >= 64);

    float* out = (float*)d_out;

    // x = lin1(node_input, node_attr)
    k_lin1<<<(n_nc + 255) / 256, 256, 0, stream>>>(node_input, node_attr, W_lin1, xbuf, n_nc);

    if (fast) {
        if (npp > N) npp = N;
        int passes = (N + npp - 1) / npp;
        npp = (N + passes - 1) / passes;

        // CSR over edge_dst (+ srcs gather)
        hipMemsetAsync(counts, 0, (size_t)N * sizeof(int), stream);
        k_hist<<<(E + 255) / 256, 256, 0, stream>>>(edge_dst, counts, E);
        k_scan<<<1, 1024, 0, stream>>>(counts, offsets, cursor, N);
        k_fill<<<(E + 255) / 256, 256, 0, stream>>>(edge_dst, edge_src, cursor, perm, srcs, E);
        // radial layer-1 for all edges, perm order
        k_hsilu<<<(E + 255) / 256, 256, 0, stream>>>(edge_features, fc_w1, fc_b1, perm, Hbuf, E);
        // pack W2 into B-fragment order
        k_prep_bfrag<<<(512 * 64 + 255) / 256, 256, 0, stream>>>(fc_w2, Bfrag);

        for (int p = 0; p < passes; ++p) {
            int n0 = p * npp;
            int nn = (n0 + npp <= N) ? npp : (N - n0);
            int M = nn * 4;
            k_zbuild<<<(nn + 3) / 4, 256, 0, stream>>>(
                Hbuf, srcs, offsets, counts, xbuf, Zbuf, xsum, n0, nn);
            k_gemm<<<(M + 63) / 64, 256, 0, stream>>>(Zbuf, Bfrag, out, n0 * 4, M);
        }
        k_node_out<<<(n_nc + 255) / 256, 256, 0, stream>>>(
            node_input, node_attr, W_sc, W_lin2, fc_b2, xsum, out, n_nc, 1);
    } else {
        hipMemsetAsync(d_out, 0, (size_t)out_size * sizeof(float), stream);
        k_edge_atomic<<<(E + EBS - 1) / EBS, EBS, 0, stream>>>(
            edge_features, fc_w1, fc_b1, fc_w2, fc_b2, edge_src, edge_dst, xbuf, out, E);
        k_node_out<<<(n_nc + 255) / 256, 256, 0, stream>>>(
            node_input, node_attr, W_sc, W_lin2, fc_b2, xsum, out, n_nc, 0);
    }
}

// Round 6
// 552.089 us; speedup vs baseline: 1.2750x; 1.2750x over previous
//
#include <hip/hip_runtime.h>
#include <math.h>

// Problem dims (fixed by reference)
#define CC 4
#define FE 32
#define HH 64
#define EBS 256
#define KEXT 544          // 512 + 32 (8 xbar cols + 24 zero pad), 17 K-steps of 32
#define ZSTRIDE 68        // uint4 per Z row (KEXT/8)

typedef __attribute__((ext_vector_type(8))) short bf16x8;
typedef __attribute__((ext_vector_type(4))) float f32x4;

// bf16 round-to-nearest-even pack
__device__ inline unsigned short f2bf(float f) {
    unsigned u = __float_as_uint(f);
    u += 0x7fffu + ((u >> 16) & 1u);
    return (unsigned short)(u >> 16);
}
__device__ inline float bf2f(unsigned short b) {
    return __uint_as_float(((unsigned)b) << 16);
}

// ---------------------------------------------------------------------------
// Kernel A: per (n,c):
//   x[n,c,j] = sum_{i,a} ni[n,c,i]*attr[n,a]*W_lin1[i,a,j]   -> xbuf
//   s[n,c,o] = c_s * sum_{i,a} ni[n,c,i]*attr[n,a]*W_sc[i,a,o] -> sbuf
// ---------------------------------------------------------------------------
__global__ __launch_bounds__(256) void k_lin1s(
    const float* __restrict__ node_input, const float* __restrict__ node_attr,
    const float* __restrict__ W_lin1, const float* __restrict__ W_sc,
    float* __restrict__ xout, float* __restrict__ sout, int n_nc)
{
    const float c_s = 0.3826834323650898f;
    __shared__ float w1l[1024];
    __shared__ float wscl[1024];
    int tid = threadIdx.x;
    #pragma unroll
    for (int it = 0; it < 4; ++it) w1l[it * 256 + tid] = W_lin1[it * 256 + tid];
    #pragma unroll
    for (int it = 0; it < 4; ++it) wscl[it * 256 + tid] = W_sc[it * 256 + tid];
    __syncthreads();

    int t0 = blockIdx.x * 256 + tid;
    bool active = (t0 < n_nc);
    int t = active ? t0 : (n_nc - 1);
    int n = t >> 2;
    float attr[16];
    #pragma unroll
    for (int a = 0; a < 16; ++a) attr[a] = node_attr[(size_t)n * 16 + a];
    float xi[8];
    #pragma unroll
    for (int i = 0; i < 8; ++i) xi[i] = node_input[(size_t)t * 8 + i];
    float xo[8] = {0.f, 0.f, 0.f, 0.f, 0.f, 0.f, 0.f, 0.f};
    float so[8] = {0.f, 0.f, 0.f, 0.f, 0.f, 0.f, 0.f, 0.f};
    #pragma unroll
    for (int i = 0; i < 8; ++i) {
        #pragma unroll
        for (int a = 0; a < 16; ++a) {
            float f = xi[i] * attr[a];
            #pragma unroll
            for (int j = 0; j < 8; ++j) {
                xo[j] += f * w1l[(i * 16 + a) * 8 + j];
                so[j] += f * wscl[(i * 16 + a) * 8 + j];
            }
        }
    }
    if (active) {
        #pragma unroll
        for (int j = 0; j < 8; ++j) xout[(size_t)t * 8 + j] = xo[j];
        #pragma unroll
        for (int j = 0; j < 8; ++j) sout[(size_t)t * 8 + j] = c_s * so[j];
    }
}

// ---------------------------------------------------------------------------
// w2n precompute: thread per (n,o):
//   w2n_ws[n*64 + o*8 + p] = c_x_scaled * sum_a attr[n,a] * W_lin2[o,a,p]
// ---------------------------------------------------------------------------
__global__ __launch_bounds__(256) void k_prep_w2n(
    const float* __restrict__ node_attr, const float* __restrict__ W_lin2,
    float* __restrict__ w2n_ws, int n8)
{
    const float c_x_scaled = 0.9238795325112867f * 0.35355339059327373f; // c_x / sqrt(8)
    __shared__ float wl2[1024];
    int tid = threadIdx.x;
    #pragma unroll
    for (int it = 0; it < 4; ++it) wl2[it * 256 + tid] = W_lin2[it * 256 + tid];
    __syncthreads();

    int t0 = blockIdx.x * 256 + tid;
    bool active = (t0 < n8);
    int t = active ? t0 : (n8 - 1);
    int n = t >> 3, o = t & 7;
    float acc[8] = {0.f, 0.f, 0.f, 0.f, 0.f, 0.f, 0.f, 0.f};
    #pragma unroll
    for (int a = 0; a < 16; ++a) {
        float fa = node_attr[(size_t)n * 16 + a];
        #pragma unroll
        for (int p = 0; p < 8; ++p)
            acc[p] += fa * wl2[(o * 16 + a) * 8 + p];
    }
    if (active) {
        float4 r0, r1;
        r0.x = c_x_scaled * acc[0]; r0.y = c_x_scaled * acc[1];
        r0.z = c_x_scaled * acc[2]; r0.w = c_x_scaled * acc[3];
        r1.x = c_x_scaled * acc[4]; r1.y = c_x_scaled * acc[5];
        r1.z = c_x_scaled * acc[6]; r1.w = c_x_scaled * acc[7];
        *reinterpret_cast<float4*>(w2n_ws + (size_t)t * 8) = r0;
        *reinterpret_cast<float4*>(w2n_ws + (size_t)t * 8 + 4) = r1;
    }
}

// ---------------------------------------------------------------------------
// CSR build over edge_dst
// ---------------------------------------------------------------------------
__global__ __launch_bounds__(256) void k_hist(
    const int* __restrict__ edge_dst, int* __restrict__ counts, int E)
{
    int e = blockIdx.x * 256 + threadIdx.x;
    if (e < E) atomicAdd(&counts[edge_dst[e]], 1);
}

// single-block shfl-based scan (16 waves of 64)
__global__ __launch_bounds__(1024) void k_scan(
    const int* __restrict__ counts, int* __restrict__ offsets,
    int* __restrict__ cursor, int N)
{
    __shared__ int wsum[16];
    __shared__ int wpre[16];
    __shared__ int s_tot;
    __shared__ int s_carry;
    int tid = threadIdx.x, wid = tid >> 6, lane = tid & 63;
    if (tid == 0) s_carry = 0;
    __syncthreads();
    for (int base = 0; base < N; base += 1024) {
        int idx = base + tid;
        int v = (idx < N) ? counts[idx] : 0;
        int x = v;
        #pragma unroll
        for (int s = 1; s < 64; s <<= 1) {
            int y = __shfl_up(x, s);
            if (lane >= s) x += y;
        }
        if (lane == 63) wsum[wid] = x;
        __syncthreads();
        if (wid == 0) {
            int wv = (lane < 16) ? wsum[lane] : 0;
            int wx = wv;
            #pragma unroll
            for (int s = 1; s < 16; s <<= 1) {
                int y = __shfl_up(wx, s);
                if (lane >= s) wx += y;
            }
            if (lane < 16) wpre[lane] = wx - wv;
            if (lane == 15) s_tot = wx;
        }
        __syncthreads();
        if (idx < N) {
            int excl = s_carry + wpre[wid] + (x - v);
            offsets[idx] = excl;
            cursor[idx] = excl;
        }
        __syncthreads();
        if (tid == 0) s_carry += s_tot;
    }
}

// fill permutation; also gather srcs into perm order
__global__ __launch_bounds__(256) void k_fill(
    const int* __restrict__ edge_dst, const int* __restrict__ edge_src,
    int* __restrict__ cursor, int* __restrict__ perm, int* __restrict__ srcs, int E)
{
    int e = blockIdx.x * 256 + threadIdx.x;
    if (e < E) {
        int pos = atomicAdd(&cursor[edge_dst[e]], 1);
        perm[pos] = e;
        srcs[pos] = edge_src[e];
    }
}

// ---------------------------------------------------------------------------
// Pack W2 (+ b2 as K-rows 512..519, zeros 520..543) into MFMA B-frag order.
// ---------------------------------------------------------------------------
__global__ __launch_bounds__(256) void k_prep_bfrag(
    const float* __restrict__ fc_w2, const float* __restrict__ fc_b2,
    unsigned short* __restrict__ Bfrag)
{
    int t = blockIdx.x * 256 + threadIdx.x;
    if (t >= KEXT * 64) return;
    int kappa = t >> 6, nu = t & 63;
    int d = nu >> 3, o = nu & 7;
    float val;
    if (kappa < 512)      val = fc_w2[(size_t)(kappa >> 3) * 512 + d * 64 + (kappa & 7) * 8 + o];
    else if (kappa < 520) val = fc_b2[d * 64 + (kappa & 7) * 8 + o];
    else                  val = 0.f;
    int kk = kappa >> 5;
    int lane = ((kappa >> 3) & 3) * 16 + (nu & 15);
    int ct = nu >> 4;
    int j = kappa & 7;
    Bfrag[(size_t)((kk * 4 + ct) * 64 + lane) * 8 + j] = f2bf(val);
}

// ---------------------------------------------------------------------------
// H build: H[p, k] = silu(ef[perm[p],:] . W1[:,k] + b1[k]) as bf16, perm order.
// ---------------------------------------------------------------------------
__global__ __launch_bounds__(256) void k_hsilu(
    const float* __restrict__ edge_features,
    const float* __restrict__ fc_w1, const float* __restrict__ fc_b1,
    const int* __restrict__ perm,
    unsigned short* __restrict__ H, int E)
{
    __shared__ float w1lds[FE * HH];
    __shared__ float b1lds[HH];
    int tid = threadIdx.x;
    #pragma unroll
    for (int it = 0; it < (FE * HH) / 256; ++it)
        w1lds[it * 256 + tid] = fc_w1[it * 256 + tid];
    if (tid < HH) b1lds[tid] = fc_b1[tid];
    __syncthreads();

    int p = blockIdx.x * 256 + tid;
    if (p >= E) return;
    int e = perm[p];

    float efv[FE];
    const float4* efp = reinterpret_cast<const float4*>(edge_features + (size_t)e * FE);
    #pragma unroll
    for (int q = 0; q < FE / 4; ++q) {
        float4 v = efp[q];
        efv[q * 4 + 0] = v.x; efv[q * 4 + 1] = v.y;
        efv[q * 4 + 2] = v.z; efv[q * 4 + 3] = v.w;
    }
    float h[HH];
    #pragma unroll
    for (int k = 0; k < HH; ++k) h[k] = b1lds[k];
    #pragma unroll
    for (int f = 0; f < FE; ++f) {
        float ev = efv[f];
        const float4* wp = reinterpret_cast<const float4*>(&w1lds[f * HH]);
        #pragma unroll
        for (int q = 0; q < HH / 4; ++q) {
            float4 w = wp[q];
            h[q * 4 + 0] += ev * w.x;
            h[q * 4 + 1] += ev * w.y;
            h[q * 4 + 2] += ev * w.z;
            h[q * 4 + 3] += ev * w.w;
        }
    }
    unsigned short* Hrow = H + (size_t)p * HH;
    #pragma unroll
    for (int q = 0; q < 8; ++q) {
        float s0 = h[q * 8 + 0], s1 = h[q * 8 + 1], s2 = h[q * 8 + 2], s3 = h[q * 8 + 3];
        float s4 = h[q * 8 + 4], s5 = h[q * 8 + 5], s6 = h[q * 8 + 6], s7 = h[q * 8 + 7];
        s0 /= (1.f + __expf(-s0)); s1 /= (1.f + __expf(-s1));
        s2 /= (1.f + __expf(-s2)); s3 /= (1.f + __expf(-s3));
        s4 /= (1.f + __expf(-s4)); s5 /= (1.f + __expf(-s5));
        s6 /= (1.f + __expf(-s6)); s7 /= (1.f + __expf(-s7));
        uint4 pk;
        pk.x = (unsigned)f2bf(s0) | ((unsigned)f2bf(s1) << 16);
        pk.y = (unsigned)f2bf(s2) | ((unsigned)f2bf(s3) << 16);
        pk.z = (unsigned)f2bf(s4) | ((unsigned)f2bf(s5) << 16);
        pk.w = (unsigned)f2bf(s6) | ((unsigned)f2bf(s7) << 16);
        reinterpret_cast<uint4*>(Hrow)[q] = pk;
    }
}

// ---------------------------------------------------------------------------
// Z build: one wave per node. lane k owns h[e,k].
// Z row (KEXT cols): [0..511] = z, [512..519] = xbar (row's c), [520..543] = 0.
// ---------------------------------------------------------------------------
__global__ __launch_bounds__(256) void k_zbuild(
    const unsigned short* __restrict__ H, const int* __restrict__ srcs,
    const int* __restrict__ offsets, const int* __restrict__ counts,
    const float* __restrict__ xin,
    unsigned short* __restrict__ Z,
    int n0, int nNodes)
{
    int node_l = blockIdx.x * 4 + (threadIdx.x >> 6);
    int lane = threadIdx.x & 63;
    if (node_l >= nNodes) return;
    int node = n0 + node_l;
    int off = offsets[node], cnt = counts[node];

    float z[CC][8];
    #pragma unroll
    for (int c = 0; c < CC; ++c)
        #pragma unroll
        for (int i = 0; i < 8; ++i) z[c][i] = 0.f;
    float xsown = 0.f;

    for (int base = 0; base < cnt; base += 64) {
        int m = (cnt - base < 64) ? (cnt - base) : 64;
        int sj = (lane < m) ? srcs[off + base + lane] : 0;
        #pragma unroll 2
        for (int j = 0; j < m; ++j) {
            int src = __shfl(sj, j);
            float hk = bf2f(H[(size_t)(off + base + j) * HH + lane]);
            const float4* xp = reinterpret_cast<const float4*>(xin + (size_t)src * 32);
            float xs[32];
            #pragma unroll
            for (int q = 0; q < 8; ++q) {
                float4 v = xp[q];
                xs[q * 4 + 0] = v.x; xs[q * 4 + 1] = v.y;
                xs[q * 4 + 2] = v.z; xs[q * 4 + 3] = v.w;
            }
            #pragma unroll
            for (int c = 0; c < CC; ++c)
                #pragma unroll
                for (int i = 0; i < 8; ++i)
                    z[c][i] += hk * xs[c * 8 + i];
            xsown += xin[(size_t)src * 32 + (lane & 31)];
        }
    }

    uint4* Zu = reinterpret_cast<uint4*>(Z);
    #pragma unroll
    for (int c = 0; c < CC; ++c) {
        uint4 pk;
        pk.x = (unsigned)f2bf(z[c][0]) | ((unsigned)f2bf(z[c][1]) << 16);
        pk.y = (unsigned)f2bf(z[c][2]) | ((unsigned)f2bf(z[c][3]) << 16);
        pk.z = (unsigned)f2bf(z[c][4]) | ((unsigned)f2bf(z[c][5]) << 16);
        pk.w = (unsigned)f2bf(z[c][6]) | ((unsigned)f2bf(z[c][7]) << 16);
        Zu[(size_t)(node_l * 4 + c) * ZSTRIDE + lane] = pk;
    }
    // xbar columns (kappa 512..519): row c gets xsown from lanes c*8..c*8+7
    float xb[8];
    #pragma unroll
    for (int i = 0; i < 8; ++i) xb[i] = __shfl(xsown, (lane & 3) * 8 + i);
    int r4 = node_l * 4;
    if (lane < 4) {
        uint4 pk;
        pk.x = (unsigned)f2bf(xb[0]) | ((unsigned)f2bf(xb[1]) << 16);
        pk.y = (unsigned)f2bf(xb[2]) | ((unsigned)f2bf(xb[3]) << 16);
        pk.z = (unsigned)f2bf(xb[4]) | ((unsigned)f2bf(xb[5]) << 16);
        pk.w = (unsigned)f2bf(xb[6]) | ((unsigned)f2bf(xb[7]) << 16);
        Zu[(size_t)(r4 + lane) * ZSTRIDE + 64] = pk;
    } else if (lane < 16) {
        int j = lane - 4;   // 12 zero-pad uint4s: rows 0..3 x slots 65..67
        uint4 zz; zz.x = 0u; zz.y = 0u; zz.z = 0u; zz.w = 0u;
        Zu[(size_t)(r4 + (j & 3)) * ZSTRIDE + 65 + (j >> 2)] = zz;
    }
}

// ---------------------------------------------------------------------------
// GEMM: agg[M,64] = Z[M,KEXT] @ B[KEXT,64], bf16 MFMA 16x16x32, fp32 out.
// kk 0..15 from LDS (64 KB cap); kk=16 (bias block) B kept in registers.
// ---------------------------------------------------------------------------
__global__ __launch_bounds__(256) void k_gemm(
    const unsigned short* __restrict__ Z, const unsigned short* __restrict__ Bfrag,
    float* __restrict__ out, int row_base, int M)
{
    __shared__ short blds[32768];
    int tid = threadIdx.x;
    #pragma unroll
    for (int it = 0; it < 16; ++it) {
        int idx = it * 256 + tid;
        reinterpret_cast<uint4*>(blds)[idx] = reinterpret_cast<const uint4*>(Bfrag)[idx];
    }
    __syncthreads();

    int w = tid >> 6, l = tid & 63;
    int rbase = blockIdx.x * 64 + w * 16;
    int arow = rbase + (l & 15);
    if (arow >= M) arow = M - 1;

    // bias-block B fragments (kk=16) from global, wave-uniform-ish
    bf16x8 bx[4];
    #pragma unroll
    for (int ct = 0; ct < 4; ++ct) {
        uint4 bv = reinterpret_cast<const uint4*>(Bfrag)[(64 + ct) * 64 + l];
        bx[ct] = *reinterpret_cast<bf16x8*>(&bv);
    }

    f32x4 acc[4];
    #pragma unroll
    for (int ct = 0; ct < 4; ++ct) acc[ct] = (f32x4){0.f, 0.f, 0.f, 0.f};

    #pragma unroll
    for (int kk = 0; kk < 16; ++kk) {
        uint4 av = reinterpret_cast<const uint4*>(Z)[(size_t)arow * ZSTRIDE + kk * 4 + (l >> 4)];
        bf16x8 a = *reinterpret_cast<bf16x8*>(&av);
        #pragma unroll
        for (int ct = 0; ct < 4; ++ct) {
            bf16x8 b = *reinterpret_cast<const bf16x8*>(&blds[(size_t)((kk * 4 + ct) * 64 + l) * 8]);
            acc[ct] = __builtin_amdgcn_mfma_f32_16x16x32_bf16(a, b, acc[ct], 0, 0, 0);
        }
    }
    {   // bias K-step
        uint4 av = reinterpret_cast<const uint4*>(Z)[(size_t)arow * ZSTRIDE + 64 + (l >> 4)];
        bf16x8 a = *reinterpret_cast<bf16x8*>(&av);
        #pragma unroll
        for (int ct = 0; ct < 4; ++ct)
            acc[ct] = __builtin_amdgcn_mfma_f32_16x16x32_bf16(a, bx[ct], acc[ct], 0, 0, 0);
    }

    #pragma unroll
    for (int ct = 0; ct < 4; ++ct) {
        #pragma unroll
        for (int v = 0; v < 4; ++v) {
            int r = rbase + (l >> 4) * 4 + v;
            if (r < M)
                out[(size_t)(row_base + r) * 64 + ct * 16 + (l & 15)] = acc[ct][v];
        }
    }
}

// ---------------------------------------------------------------------------
// Kernel C: one wave per node, pure-register shuffle epilogue.
//   out[n,c,d,p] = sbuf[n,c,p] + sum_o agg[n,c,d,o] * w2n_ws[n,o,p]
// (sbuf pre-scaled by c_s; w2n_ws pre-scaled by c_x/sqrt(8); bias already in agg)
// ---------------------------------------------------------------------------
__global__ __launch_bounds__(256) void k_node_out(
    const float* __restrict__ sbuf, const float* __restrict__ w2n_ws,
    float* __restrict__ out, int N)
{
    int node = blockIdx.x * 4 + (threadIdx.x >> 6);
    int lane = threadIdx.x & 63;
    if (node >= N) return;
    int d = lane >> 3, p = lane & 7;

    float w2 = w2n_ws[(size_t)node * 64 + lane];            // w2n[o=lane>>3, p=lane&7]
    float s_own = sbuf[(size_t)node * 32 + (lane & 31)];    // s[c=lane>>3&3, o=lane&7]

    float w2sh[8];
    #pragma unroll
    for (int o = 0; o < 8; ++o) w2sh[o] = __shfl(w2, o * 8 + p);

    float* rowp = out + (size_t)node * 256;
    #pragma unroll
    for (int c = 0; c < CC; ++c) {
        float a_own = rowp[c * 64 + lane];                  // agg[c, d=lane>>3, o=lane&7]
        float res = 0.f;
        #pragma unroll
        for (int o = 0; o < 8; ++o)
            res += __shfl(a_own, d * 8 + o) * w2sh[o];
        float sval = __shfl(s_own, c * 8 + p);
        rowp[c * 64 + lane] = sval + res;
    }
}

// ---------------------------------------------------------------------------
// Fallback edge kernel (global atomics) — only if ws too small.
// agg includes bias (t starts from fc_b2), so same epilogue applies.
// ---------------------------------------------------------------------------
__global__ __launch_bounds__(EBS) void k_edge_atomic(
    const float* __restrict__ edge_features,
    const float* __restrict__ fc_w1, const float* __restrict__ fc_b1,
    const float* __restrict__ fc_w2, const float* __restrict__ fc_b2,
    const int* __restrict__ edge_src, const int* __restrict__ edge_dst,
    const float* __restrict__ xin, float* __restrict__ agg, int E)
{
    __shared__ float hlds[HH * EBS];
    int e = blockIdx.x * EBS + threadIdx.x;
    if (e >= E) return;
    float h[HH];
    #pragma unroll
    for (int k = 0; k < HH; ++k) h[k] = fc_b1[k];
    const float4* efp = reinterpret_cast<const float4*>(edge_features + (size_t)e * FE);
    #pragma unroll
    for (int fq = 0; fq < FE / 4; ++fq) {
        float4 efv = efp[fq];
        float ev[4] = {efv.x, efv.y, efv.z, efv.w};
        #pragma unroll
        for (int fs = 0; fs < 4; ++fs) {
            float evv = ev[fs];
            const float4* w1p = reinterpret_cast<const float4*>(fc_w1 + (fq * 4 + fs) * HH);
            #pragma unroll
            for (int q = 0; q < HH / 4; ++q) {
                float4 w = w1p[q];
                h[q * 4 + 0] += evv * w.x;
                h[q * 4 + 1] += evv * w.y;
                h[q * 4 + 2] += evv * w.z;
                h[q * 4 + 3] += evv * w.w;
            }
        }
    }
    #pragma unroll
    for (int k = 0; k < HH; ++k) {
        float v = h[k];
        hlds[k * EBS + threadIdx.x] = v / (1.f + __expf(-v));
    }
    int src = edge_src[e], dst = edge_dst[e];
    float xs[32];
    const float4* xp = reinterpret_cast<const float4*>(xin + (size_t)src * 32);
    #pragma unroll
    for (int q = 0; q < 8; ++q) {
        float4 v = xp[q];
        xs[q * 4 + 0] = v.x; xs[q * 4 + 1] = v.y;
        xs[q * 4 + 2] = v.z; xs[q * 4 + 3] = v.w;
    }
    float* outp = agg + (size_t)dst * 256;
    #pragma unroll 1
    for (int d = 0; d < 8; ++d) {
        float t[64];
        const float4* b2p = reinterpret_cast<const float4*>(fc_b2 + d * 64);
        #pragma unroll
        for (int q = 0; q < 16; ++q) {
            float4 v = b2p[q];
            t[q * 4 + 0] = v.x; t[q * 4 + 1] = v.y;
            t[q * 4 + 2] = v.z; t[q * 4 + 3] = v.w;
        }
        for (int k = 0; k < HH; ++k) {
            float hv = hlds[k * EBS + threadIdx.x];
            const float4* wp = reinterpret_cast<const float4*>(fc_w2 + (size_t)k * 512 + d * 64);
            #pragma unroll
            for (int q = 0; q < 16; ++q) {
                float4 w = wp[q];
                t[q * 4 + 0] += hv * w.x;
                t[q * 4 + 1] += hv * w.y;
                t[q * 4 + 2] += hv * w.z;
                t[q * 4 + 3] += hv * w.w;
            }
        }
        #pragma unroll
        for (int c = 0; c < CC; ++c) {
            #pragma unroll
            for (int o = 0; o < 8; ++o) {
                float acc = 0.f;
                #pragma unroll
                for (int i = 0; i < 8; ++i) acc += xs[c * 8 + i] * t[i * 8 + o];
                atomicAdd(outp + c * 64 + d * 8 + o, acc);
            }
        }
    }
}

// ---------------------------------------------------------------------------
extern "C" void kernel_launch(void* const* d_in, const int* in_sizes, int n_in,
                              void* d_out, int out_size, void* d_ws, size_t ws_size,
                              hipStream_t stream)
{
    const float* node_input    = (const float*)d_in[0];
    const float* node_attr     = (const float*)d_in[1];
    const float* edge_features = (const float*)d_in[2];
    const float* W_sc          = (const float*)d_in[3];
    const float* W_lin1        = (const float*)d_in[4];
    const float* W_lin2        = (const float*)d_in[5];
    const float* fc_w1         = (const float*)d_in[6];
    const float* fc_b1         = (const float*)d_in[7];
    const float* fc_w2         = (const float*)d_in[8];
    const float* fc_b2         = (const float*)d_in[9];
    const int*   edge_src      = (const int*)d_in[10];
    const int*   edge_dst      = (const int*)d_in[11];

    const int N = in_sizes[1] / 16;
    const int E = in_sizes[10];
    const int n_nc = N * CC;

    char* ws = (char*)d_ws;
    size_t off = 0;
    auto take = [&](size_t bytes) { char* p = ws + off; off += (bytes + 15) & ~(size_t)15; return p; };
    float* xbuf            = (float*)take((size_t)N * 32 * sizeof(float));
    float* sbuf            = (float*)take((size_t)N * 32 * sizeof(float));
    float* w2n_ws          = (float*)take((size_t)N * 64 * sizeof(float));
    int*   counts          = (int*)take((size_t)N * sizeof(int));
    int*   offsets         = (int*)take((size_t)N * sizeof(int));
    int*   cursor          = (int*)take((size_t)N * sizeof(int));
    int*   perm            = (int*)take((size_t)E * sizeof(int));
    int*   srcs            = (int*)take((size_t)E * sizeof(int));
    unsigned short* Bfrag  = (unsigned short*)take((size_t)17 * 4 * 64 * 8 * sizeof(unsigned short));
    unsigned short* Hbuf   = (unsigned short*)take((size_t)E * HH * sizeof(unsigned short));
    size_t fixed_off = off;
    unsigned short* Zbuf   = (unsigned short*)(ws + fixed_off);

    long long avail = (long long)ws_size - (long long)fixed_off;
    int npp = (avail > 0) ? (int)(avail / (4 * KEXT * 2)) : 0;   // bytes per node
    bool fast = (npp >= 64);

    float* out = (float*)d_out;

    // node prep: x (lin1) and c_s*s (sc), plus per-node w2n
    k_lin1s<<<(n_nc + 255) / 256, 256, 0, stream>>>(
        node_input, node_attr, W_lin1, W_sc, xbuf, sbuf, n_nc);
    k_prep_w2n<<<(N * 8 + 255) / 256, 256, 0, stream>>>(
        node_attr, W_lin2, w2n_ws, N * 8);

    if (fast) {
        if (npp > N) npp = N;
        int passes = (N + npp - 1) / npp;
        npp = (N + passes - 1) / passes;

        // CSR over edge_dst (+ srcs gather)
        hipMemsetAsync(counts, 0, (size_t)N * sizeof(int), stream);
        k_hist<<<(E + 255) / 256, 256, 0, stream>>>(edge_dst, counts, E);
        k_scan<<<1, 1024, 0, stream>>>(counts, offsets, cursor, N);
        k_fill<<<(E + 255) / 256, 256, 0, stream>>>(edge_dst, edge_src, cursor, perm, srcs, E);
        // radial layer-1 for all edges, perm order
        k_hsilu<<<(E + 255) / 256, 256, 0, stream>>>(edge_features, fc_w1, fc_b1, perm, Hbuf, E);
        // pack W2+b2 into B-fragment order
        k_prep_bfrag<<<(KEXT * 64 + 255) / 256, 256, 0, stream>>>(fc_w2, fc_b2, Bfrag);

        for (int p = 0; p < passes; ++p) {
            int n0 = p * npp;
            int nn = (n0 + npp <= N) ? npp : (N - n0);
            int M = nn * 4;
            k_zbuild<<<(nn + 3) / 4, 256, 0, stream>>>(
                Hbuf, srcs, offsets, counts, xbuf, Zbuf, n0, nn);
            k_gemm<<<(M + 63) / 64, 256, 0, stream>>>(Zbuf, Bfrag, out, n0 * 4, M);
        }
    } else {
        hipMemsetAsync(d_out, 0, (size_t)out_size * sizeof(float), stream);
        k_edge_atomic<<<(E + EBS - 1) / EBS, EBS, 0, stream>>>(
            edge_features, fc_w1, fc_b1, fc_w2, fc_b2, edge_src, edge_dst, xbuf, out, E);
    }

    // epilogue: per-node shuffle lin2 + self-connection (in place on out)
    k_node_out<<<(N + 3) / 4, 256, 0, stream>>>(sbuf, w2n_ws, out, N);
}

// Round 7
// 439.012 us; speedup vs baseline: 1.6034x; 1.2576x over previous
//
#include <hip/hip_runtime.h>
#include <math.h>

// Problem dims (fixed by reference)
#define CC 4
#define FE 32
#define HH 64
#define EBS 256
#define KEXT 544          // 512 + 32 (8 xbar cols + 24 zero pad), 17 K-steps of 32
#define ZSTRIDE 68        // uint4 per Z row (KEXT/8)

typedef __attribute__((ext_vector_type(8))) short bf16x8;
typedef __attribute__((ext_vector_type(4))) float f32x4;

// bf16 round-to-nearest-even pack
__device__ inline unsigned short f2bf(float f) {
    unsigned u = __float_as_uint(f);
    u += 0x7fffu + ((u >> 16) & 1u);
    return (unsigned short)(u >> 16);
}
__device__ inline float bf2f(unsigned short b) {
    return __uint_as_float(((unsigned)b) << 16);
}

// ---------------------------------------------------------------------------
// Node prep (one wave per node, shuffle-based, low-VGPR):
//   wbar1[i,j] = sum_a attr[a] W_lin1[i,a,j]      (lane = i*8+j, 16 FMA)
//   wbsc [i,j] = sum_a attr[a] W_sc  [i,a,j]
//   w2n  [o,p] = sum_a attr[a] W_lin2[o,a,p]  -> w2n_ws (scaled c_x/sqrt8)
//   x[c,j] = sum_i ni[c,i] wbar1[i,j]         -> xbuf
//   s[c,j] = c_s * sum_i ni[c,i] wbsc[i,j]    -> sbuf
// ---------------------------------------------------------------------------
__global__ __launch_bounds__(256) void k_nodeprep(
    const float* __restrict__ node_input, const float* __restrict__ node_attr,
    const float* __restrict__ W_lin1, const float* __restrict__ W_sc,
    const float* __restrict__ W_lin2,
    float* __restrict__ xbuf, float* __restrict__ sbuf,
    float* __restrict__ w2n_ws, int N)
{
    const float c_s = 0.3826834323650898f;
    const float c_x_scaled = 0.9238795325112867f * 0.35355339059327373f; // c_x/sqrt(8)
    int node = blockIdx.x * 4 + (threadIdx.x >> 6);
    int lane = threadIdx.x & 63;
    if (node >= N) return;

    float attr_own = (lane < 16) ? node_attr[(size_t)node * 16 + lane] : 0.f;
    float ni_own   = (lane < 32) ? node_input[(size_t)node * 32 + lane] : 0.f; // lane=c*8+i

    int iw = lane >> 3, jw = lane & 7;   // this lane's (i,j) / (o,p)
    float wb1 = 0.f, wbs = 0.f, w2n = 0.f;
    #pragma unroll
    for (int a = 0; a < 16; ++a) {
        float fa = __shfl(attr_own, a);
        int idx = (iw * 16 + a) * 8 + jw;
        wb1 += fa * W_lin1[idx];
        wbs += fa * W_sc[idx];
        w2n += fa * W_lin2[idx];
    }
    w2n_ws[(size_t)node * 64 + lane] = c_x_scaled * w2n;

    // x/s for lane<32 (c = lane>>3, j = lane&7); lanes>=32 compute duplicates
    int c_ = (lane >> 3) & 3, jo = lane & 7;
    float xo = 0.f, so = 0.f;
    #pragma unroll
    for (int i = 0; i < 8; ++i) {
        float niv = __shfl(ni_own, c_ * 8 + i);
        xo += niv * __shfl(wb1, i * 8 + jo);
        so += niv * __shfl(wbs, i * 8 + jo);
    }
    if (lane < 32) {
        xbuf[(size_t)node * 32 + lane] = xo;
        sbuf[(size_t)node * 32 + lane] = c_s * so;
    }
}

// ---------------------------------------------------------------------------
// CSR build over edge_dst
// ---------------------------------------------------------------------------
__global__ __launch_bounds__(256) void k_hist(
    const int* __restrict__ edge_dst, int* __restrict__ counts, int E)
{
    int e = blockIdx.x * 256 + threadIdx.x;
    if (e < E) atomicAdd(&counts[edge_dst[e]], 1);
}

// single-block shfl-based scan (16 waves of 64)
__global__ __launch_bounds__(1024) void k_scan(
    const int* __restrict__ counts, int* __restrict__ offsets,
    int* __restrict__ cursor, int N)
{
    __shared__ int wsum[16];
    __shared__ int wpre[16];
    __shared__ int s_tot;
    __shared__ int s_carry;
    int tid = threadIdx.x, wid = tid >> 6, lane = tid & 63;
    if (tid == 0) s_carry = 0;
    __syncthreads();
    for (int base = 0; base < N; base += 1024) {
        int idx = base + tid;
        int v = (idx < N) ? counts[idx] : 0;
        int x = v;
        #pragma unroll
        for (int s = 1; s < 64; s <<= 1) {
            int y = __shfl_up(x, s);
            if (lane >= s) x += y;
        }
        if (lane == 63) wsum[wid] = x;
        __syncthreads();
        if (wid == 0) {
            int wv = (lane < 16) ? wsum[lane] : 0;
            int wx = wv;
            #pragma unroll
            for (int s = 1; s < 16; s <<= 1) {
                int y = __shfl_up(wx, s);
                if (lane >= s) wx += y;
            }
            if (lane < 16) wpre[lane] = wx - wv;
            if (lane == 15) s_tot = wx;
        }
        __syncthreads();
        if (idx < N) {
            int excl = s_carry + wpre[wid] + (x - v);
            offsets[idx] = excl;
            cursor[idx] = excl;
        }
        __syncthreads();
        if (tid == 0) s_carry += s_tot;
    }
}

// fill permutation; also gather srcs into perm order
__global__ __launch_bounds__(256) void k_fill(
    const int* __restrict__ edge_dst, const int* __restrict__ edge_src,
    int* __restrict__ cursor, int* __restrict__ perm, int* __restrict__ srcs, int E)
{
    int e = blockIdx.x * 256 + threadIdx.x;
    if (e < E) {
        int pos = atomicAdd(&cursor[edge_dst[e]], 1);
        perm[pos] = e;
        srcs[pos] = edge_src[e];
    }
}

// ---------------------------------------------------------------------------
// Pack W2 (+ b2 as K-rows 512..519, zeros 520..543) into MFMA B-frag order.
// ---------------------------------------------------------------------------
__global__ __launch_bounds__(256) void k_prep_bfrag(
    const float* __restrict__ fc_w2, const float* __restrict__ fc_b2,
    unsigned short* __restrict__ Bfrag)
{
    int t = blockIdx.x * 256 + threadIdx.x;
    if (t >= KEXT * 64) return;
    int kappa = t >> 6, nu = t & 63;
    int d = nu >> 3, o = nu & 7;
    float val;
    if (kappa < 512)      val = fc_w2[(size_t)(kappa >> 3) * 512 + d * 64 + (kappa & 7) * 8 + o];
    else if (kappa < 520) val = fc_b2[d * 64 + (kappa & 7) * 8 + o];
    else                  val = 0.f;
    int kk = kappa >> 5;
    int lane = ((kappa >> 3) & 3) * 16 + (nu & 15);
    int ct = nu >> 4;
    int j = kappa & 7;
    Bfrag[(size_t)((kk * 4 + ct) * 64 + lane) * 8 + j] = f2bf(val);
}

// ---------------------------------------------------------------------------
// H build: H[p, k] = silu(ef[perm[p],:] . W1[:,k] + b1[k]) as bf16, perm order.
// ---------------------------------------------------------------------------
__global__ __launch_bounds__(256) void k_hsilu(
    const float* __restrict__ edge_features,
    const float* __restrict__ fc_w1, const float* __restrict__ fc_b1,
    const int* __restrict__ perm,
    unsigned short* __restrict__ H, int E)
{
    __shared__ float w1lds[FE * HH];
    __shared__ float b1lds[HH];
    int tid = threadIdx.x;
    #pragma unroll
    for (int it = 0; it < (FE * HH) / 256; ++it)
        w1lds[it * 256 + tid] = fc_w1[it * 256 + tid];
    if (tid < HH) b1lds[tid] = fc_b1[tid];
    __syncthreads();

    int p = blockIdx.x * 256 + tid;
    if (p >= E) return;
    int e = perm[p];

    float efv[FE];
    const float4* efp = reinterpret_cast<const float4*>(edge_features + (size_t)e * FE);
    #pragma unroll
    for (int q = 0; q < FE / 4; ++q) {
        float4 v = efp[q];
        efv[q * 4 + 0] = v.x; efv[q * 4 + 1] = v.y;
        efv[q * 4 + 2] = v.z; efv[q * 4 + 3] = v.w;
    }
    float h[HH];
    #pragma unroll
    for (int k = 0; k < HH; ++k) h[k] = b1lds[k];
    #pragma unroll
    for (int f = 0; f < FE; ++f) {
        float ev = efv[f];
        const float4* wp = reinterpret_cast<const float4*>(&w1lds[f * HH]);
        #pragma unroll
        for (int q = 0; q < HH / 4; ++q) {
            float4 w = wp[q];
            h[q * 4 + 0] += ev * w.x;
            h[q * 4 + 1] += ev * w.y;
            h[q * 4 + 2] += ev * w.z;
            h[q * 4 + 3] += ev * w.w;
        }
    }
    unsigned short* Hrow = H + (size_t)p * HH;
    #pragma unroll
    for (int q = 0; q < 8; ++q) {
        float s0 = h[q * 8 + 0], s1 = h[q * 8 + 1], s2 = h[q * 8 + 2], s3 = h[q * 8 + 3];
        float s4 = h[q * 8 + 4], s5 = h[q * 8 + 5], s6 = h[q * 8 + 6], s7 = h[q * 8 + 7];
        s0 /= (1.f + __expf(-s0)); s1 /= (1.f + __expf(-s1));
        s2 /= (1.f + __expf(-s2)); s3 /= (1.f + __expf(-s3));
        s4 /= (1.f + __expf(-s4)); s5 /= (1.f + __expf(-s5));
        s6 /= (1.f + __expf(-s6)); s7 /= (1.f + __expf(-s7));
        uint4 pk;
        pk.x = (unsigned)f2bf(s0) | ((unsigned)f2bf(s1) << 16);
        pk.y = (unsigned)f2bf(s2) | ((unsigned)f2bf(s3) << 16);
        pk.z = (unsigned)f2bf(s4) | ((unsigned)f2bf(s5) << 16);
        pk.w = (unsigned)f2bf(s6) | ((unsigned)f2bf(s7) << 16);
        reinterpret_cast<uint4*>(Hrow)[q] = pk;
    }
}

// ---------------------------------------------------------------------------
// Z build: one wave per node. lane k owns h[e,k].
// Z row (KEXT cols): [0..511] = z, [512..519] = xbar (row's c), [520..543] = 0.
// ---------------------------------------------------------------------------
__global__ __launch_bounds__(256) void k_zbuild(
    const unsigned short* __restrict__ H, const int* __restrict__ srcs,
    const int* __restrict__ offsets, const int* __restrict__ counts,
    const float* __restrict__ xin,
    unsigned short* __restrict__ Z,
    int n0, int nNodes)
{
    int node_l = blockIdx.x * 4 + (threadIdx.x >> 6);
    int lane = threadIdx.x & 63;
    if (node_l >= nNodes) return;
    int node = n0 + node_l;
    int off = offsets[node], cnt = counts[node];

    float z[CC][8];
    #pragma unroll
    for (int c = 0; c < CC; ++c)
        #pragma unroll
        for (int i = 0; i < 8; ++i) z[c][i] = 0.f;
    float xsown = 0.f;

    for (int base = 0; base < cnt; base += 64) {
        int m = (cnt - base < 64) ? (cnt - base) : 64;
        int sj = (lane < m) ? srcs[off + base + lane] : 0;
        #pragma unroll 2
        for (int j = 0; j < m; ++j) {
            int src = __shfl(sj, j);
            float hk = bf2f(H[(size_t)(off + base + j) * HH + lane]);
            const float4* xp = reinterpret_cast<const float4*>(xin + (size_t)src * 32);
            float xs[32];
            #pragma unroll
            for (int q = 0; q < 8; ++q) {
                float4 v = xp[q];
                xs[q * 4 + 0] = v.x; xs[q * 4 + 1] = v.y;
                xs[q * 4 + 2] = v.z; xs[q * 4 + 3] = v.w;
            }
            #pragma unroll
            for (int c = 0; c < CC; ++c)
                #pragma unroll
                for (int i = 0; i < 8; ++i)
                    z[c][i] += hk * xs[c * 8 + i];
            xsown += xin[(size_t)src * 32 + (lane & 31)];
        }
    }

    uint4* Zu = reinterpret_cast<uint4*>(Z);
    #pragma unroll
    for (int c = 0; c < CC; ++c) {
        uint4 pk;
        pk.x = (unsigned)f2bf(z[c][0]) | ((unsigned)f2bf(z[c][1]) << 16);
        pk.y = (unsigned)f2bf(z[c][2]) | ((unsigned)f2bf(z[c][3]) << 16);
        pk.z = (unsigned)f2bf(z[c][4]) | ((unsigned)f2bf(z[c][5]) << 16);
        pk.w = (unsigned)f2bf(z[c][6]) | ((unsigned)f2bf(z[c][7]) << 16);
        Zu[(size_t)(node_l * 4 + c) * ZSTRIDE + lane] = pk;
    }
    // xbar columns (kappa 512..519): row c gets xsown from lanes c*8..c*8+7
    float xb[8];
    #pragma unroll
    for (int i = 0; i < 8; ++i) xb[i] = __shfl(xsown, (lane & 3) * 8 + i);
    int r4 = node_l * 4;
    if (lane < 4) {
        uint4 pk;
        pk.x = (unsigned)f2bf(xb[0]) | ((unsigned)f2bf(xb[1]) << 16);
        pk.y = (unsigned)f2bf(xb[2]) | ((unsigned)f2bf(xb[3]) << 16);
        pk.z = (unsigned)f2bf(xb[4]) | ((unsigned)f2bf(xb[5]) << 16);
        pk.w = (unsigned)f2bf(xb[6]) | ((unsigned)f2bf(xb[7]) << 16);
        Zu[(size_t)(r4 + lane) * ZSTRIDE + 64] = pk;
    } else if (lane < 16) {
        int j = lane - 4;   // 12 zero-pad uint4s: rows 0..3 x slots 65..67
        uint4 zz; zz.x = 0u; zz.y = 0u; zz.z = 0u; zz.w = 0u;
        Zu[(size_t)(r4 + (j & 3)) * ZSTRIDE + 65 + (j >> 2)] = zz;
    }
}

// ---------------------------------------------------------------------------
// GEMM: agg[M,64] = Z[M,KEXT] @ B[KEXT,64], bf16 MFMA 16x16x32, fp32 out.
// kk 0..15 from LDS (64 KB cap); kk=16 (bias block) B kept in registers.
// ---------------------------------------------------------------------------
__global__ __launch_bounds__(256) void k_gemm(
    const unsigned short* __restrict__ Z, const unsigned short* __restrict__ Bfrag,
    float* __restrict__ out, int row_base, int M)
{
    __shared__ short blds[32768];
    int tid = threadIdx.x;
    #pragma unroll
    for (int it = 0; it < 16; ++it) {
        int idx = it * 256 + tid;
        reinterpret_cast<uint4*>(blds)[idx] = reinterpret_cast<const uint4*>(Bfrag)[idx];
    }
    __syncthreads();

    int w = tid >> 6, l = tid & 63;
    int rbase = blockIdx.x * 64 + w * 16;
    int arow = rbase + (l & 15);
    if (arow >= M) arow = M - 1;

    // bias-block B fragments (kk=16) from global
    bf16x8 bx[4];
    #pragma unroll
    for (int ct = 0; ct < 4; ++ct) {
        uint4 bv = reinterpret_cast<const uint4*>(Bfrag)[(64 + ct) * 64 + l];
        bx[ct] = *reinterpret_cast<bf16x8*>(&bv);
    }

    f32x4 acc[4];
    #pragma unroll
    for (int ct = 0; ct < 4; ++ct) acc[ct] = (f32x4){0.f, 0.f, 0.f, 0.f};

    #pragma unroll
    for (int kk = 0; kk < 16; ++kk) {
        uint4 av = reinterpret_cast<const uint4*>(Z)[(size_t)arow * ZSTRIDE + kk * 4 + (l >> 4)];
        bf16x8 a = *reinterpret_cast<bf16x8*>(&av);
        #pragma unroll
        for (int ct = 0; ct < 4; ++ct) {
            bf16x8 b = *reinterpret_cast<const bf16x8*>(&blds[(size_t)((kk * 4 + ct) * 64 + l) * 8]);
            acc[ct] = __builtin_amdgcn_mfma_f32_16x16x32_bf16(a, b, acc[ct], 0, 0, 0);
        }
    }
    {   // bias K-step
        uint4 av = reinterpret_cast<const uint4*>(Z)[(size_t)arow * ZSTRIDE + 64 + (l >> 4)];
        bf16x8 a = *reinterpret_cast<bf16x8*>(&av);
        #pragma unroll
        for (int ct = 0; ct < 4; ++ct)
            acc[ct] = __builtin_amdgcn_mfma_f32_16x16x32_bf16(a, bx[ct], acc[ct], 0, 0, 0);
    }

    #pragma unroll
    for (int ct = 0; ct < 4; ++ct) {
        #pragma unroll
        for (int v = 0; v < 4; ++v) {
            int r = rbase + (l >> 4) * 4 + v;
            if (r < M)
                out[(size_t)(row_base + r) * 64 + ct * 16 + (l & 15)] = acc[ct][v];
        }
    }
}

// ---------------------------------------------------------------------------
// Kernel C: one wave per node, pure-register shuffle epilogue.
//   out[n,c,d,p] = sbuf[n,c,p] + sum_o agg[n,c,d,o] * w2n_ws[n,o,p]
// ---------------------------------------------------------------------------
__global__ __launch_bounds__(256) void k_node_out(
    const float* __restrict__ sbuf, const float* __restrict__ w2n_ws,
    float* __restrict__ out, int N)
{
    int node = blockIdx.x * 4 + (threadIdx.x >> 6);
    int lane = threadIdx.x & 63;
    if (node >= N) return;
    int d = lane >> 3, p = lane & 7;

    float w2 = w2n_ws[(size_t)node * 64 + lane];            // w2n[o=lane>>3, p=lane&7]
    float s_own = sbuf[(size_t)node * 32 + (lane & 31)];    // s[c=lane>>3&3, o=lane&7]

    float w2sh[8];
    #pragma unroll
    for (int o = 0; o < 8; ++o) w2sh[o] = __shfl(w2, o * 8 + p);

    float* rowp = out + (size_t)node * 256;
    #pragma unroll
    for (int c = 0; c < CC; ++c) {
        float a_own = rowp[c * 64 + lane];                  // agg[c, d=lane>>3, o=lane&7]
        float res = 0.f;
        #pragma unroll
        for (int o = 0; o < 8; ++o)
            res += __shfl(a_own, d * 8 + o) * w2sh[o];
        float sval = __shfl(s_own, c * 8 + p);
        rowp[c * 64 + lane] = sval + res;
    }
}

// ---------------------------------------------------------------------------
// Fallback edge kernel (global atomics) — only if ws too small.
// agg includes bias (t starts from fc_b2), so same epilogue applies.
// ---------------------------------------------------------------------------
__global__ __launch_bounds__(EBS) void k_edge_atomic(
    const float* __restrict__ edge_features,
    const float* __restrict__ fc_w1, const float* __restrict__ fc_b1,
    const float* __restrict__ fc_w2, const float* __restrict__ fc_b2,
    const int* __restrict__ edge_src, const int* __restrict__ edge_dst,
    const float* __restrict__ xin, float* __restrict__ agg, int E)
{
    __shared__ float hlds[HH * EBS];
    int e = blockIdx.x * EBS + threadIdx.x;
    if (e >= E) return;
    float h[HH];
    #pragma unroll
    for (int k = 0; k < HH; ++k) h[k] = fc_b1[k];
    const float4* efp = reinterpret_cast<const float4*>(edge_features + (size_t)e * FE);
    #pragma unroll
    for (int fq = 0; fq < FE / 4; ++fq) {
        float4 efv = efp[fq];
        float ev[4] = {efv.x, efv.y, efv.z, efv.w};
        #pragma unroll
        for (int fs = 0; fs < 4; ++fs) {
            float evv = ev[fs];
            const float4* w1p = reinterpret_cast<const float4*>(fc_w1 + (fq * 4 + fs) * HH);
            #pragma unroll
            for (int q = 0; q < HH / 4; ++q) {
                float4 w = w1p[q];
                h[q * 4 + 0] += evv * w.x;
                h[q * 4 + 1] += evv * w.y;
                h[q * 4 + 2] += evv * w.z;
                h[q * 4 + 3] += evv * w.w;
            }
        }
    }
    #pragma unroll
    for (int k = 0; k < HH; ++k) {
        float v = h[k];
        hlds[k * EBS + threadIdx.x] = v / (1.f + __expf(-v));
    }
    int src = edge_src[e], dst = edge_dst[e];
    float xs[32];
    const float4* xp = reinterpret_cast<const float4*>(xin + (size_t)src * 32);
    #pragma unroll
    for (int q = 0; q < 8; ++q) {
        float4 v = xp[q];
        xs[q * 4 + 0] = v.x; xs[q * 4 + 1] = v.y;
        xs[q * 4 + 2] = v.z; xs[q * 4 + 3] = v.w;
    }
    float* outp = agg + (size_t)dst * 256;
    #pragma unroll 1
    for (int d = 0; d < 8; ++d) {
        float t[64];
        const float4* b2p = reinterpret_cast<const float4*>(fc_b2 + d * 64);
        #pragma unroll
        for (int q = 0; q < 16; ++q) {
            float4 v = b2p[q];
            t[q * 4 + 0] = v.x; t[q * 4 + 1] = v.y;
            t[q * 4 + 2] = v.z; t[q * 4 + 3] = v.w;
        }
        for (int k = 0; k < HH; ++k) {
            float hv = hlds[k * EBS + threadIdx.x];
            const float4* wp = reinterpret_cast<const float4*>(fc_w2 + (size_t)k * 512 + d * 64);
            #pragma unroll
            for (int q = 0; q < 16; ++q) {
                float4 w = wp[q];
                t[q * 4 + 0] += hv * w.x;
                t[q * 4 + 1] += hv * w.y;
                t[q * 4 + 2] += hv * w.z;
                t[q * 4 + 3] += hv * w.w;
            }
        }
        #pragma unroll
        for (int c = 0; c < CC; ++c) {
            #pragma unroll
            for (int o = 0; o < 8; ++o) {
                float acc = 0.f;
                #pragma unroll
                for (int i = 0; i < 8; ++i) acc += xs[c * 8 + i] * t[i * 8 + o];
                atomicAdd(outp + c * 64 + d * 8 + o, acc);
            }
        }
    }
}

// ---------------------------------------------------------------------------
extern "C" void kernel_launch(void* const* d_in, const int* in_sizes, int n_in,
                              void* d_out, int out_size, void* d_ws, size_t ws_size,
                              hipStream_t stream)
{
    const float* node_input    = (const float*)d_in[0];
    const float* node_attr     = (const float*)d_in[1];
    const float* edge_features = (const float*)d_in[2];
    const float* W_sc          = (const float*)d_in[3];
    const float* W_lin1        = (const float*)d_in[4];
    const float* W_lin2        = (const float*)d_in[5];
    const float* fc_w1         = (const float*)d_in[6];
    const float* fc_b1         = (const float*)d_in[7];
    const float* fc_w2         = (const float*)d_in[8];
    const float* fc_b2         = (const float*)d_in[9];
    const int*   edge_src      = (const int*)d_in[10];
    const int*   edge_dst      = (const int*)d_in[11];

    const int N = in_sizes[1] / 16;
    const int E = in_sizes[10];

    char* ws = (char*)d_ws;
    size_t off = 0;
    auto take = [&](size_t bytes) { char* p = ws + off; off += (bytes + 15) & ~(size_t)15; return p; };
    float* xbuf            = (float*)take((size_t)N * 32 * sizeof(float));
    float* sbuf            = (float*)take((size_t)N * 32 * sizeof(float));
    float* w2n_ws          = (float*)take((size_t)N * 64 * sizeof(float));
    int*   counts          = (int*)take((size_t)N * sizeof(int));
    int*   offsets         = (int*)take((size_t)N * sizeof(int));
    int*   cursor          = (int*)take((size_t)N * sizeof(int));
    int*   perm            = (int*)take((size_t)E * sizeof(int));
    int*   srcs            = (int*)take((size_t)E * sizeof(int));
    unsigned short* Bfrag  = (unsigned short*)take((size_t)17 * 4 * 64 * 8 * sizeof(unsigned short));
    unsigned short* Hbuf   = (unsigned short*)take((size_t)E * HH * sizeof(unsigned short));
    size_t fixed_off = off;
    unsigned short* Zbuf   = (unsigned short*)(ws + fixed_off);

    long long avail = (long long)ws_size - (long long)fixed_off;
    int npp = (avail > 0) ? (int)(avail / (4 * KEXT * 2)) : 0;   // bytes per node
    bool fast = (npp >= 64);

    float* out = (float*)d_out;

    // node prep: x, c_s*s, w2n (one wave per node, shuffle-based)
    k_nodeprep<<<(N + 3) / 4, 256, 0, stream>>>(
        node_input, node_attr, W_lin1, W_sc, W_lin2, xbuf, sbuf, w2n_ws, N);

    if (fast) {
        if (npp > N) npp = N;
        int passes = (N + npp - 1) / npp;
        npp = (N + passes - 1) / passes;

        // CSR over edge_dst (+ srcs gather)
        hipMemsetAsync(counts, 0, (size_t)N * sizeof(int), stream);
        k_hist<<<(E + 255) / 256, 256, 0, stream>>>(edge_dst, counts, E);
        k_scan<<<1, 1024, 0, stream>>>(counts, offsets, cursor, N);
        k_fill<<<(E + 255) / 256, 256, 0, stream>>>(edge_dst, edge_src, cursor, perm, srcs, E);
        // radial layer-1 for all edges, perm order
        k_hsilu<<<(E + 255) / 256, 256, 0, stream>>>(edge_features, fc_w1, fc_b1, perm, Hbuf, E);
        // pack W2+b2 into B-fragment order
        k_prep_bfrag<<<(KEXT * 64 + 255) / 256, 256, 0, stream>>>(fc_w2, fc_b2, Bfrag);

        for (int p = 0; p < passes; ++p) {
            int n0 = p * npp;
            int nn = (n0 + npp <= N) ? npp : (N - n0);
            int M = nn * 4;
            k_zbuild<<<(nn + 3) / 4, 256, 0, stream>>>(
                Hbuf, srcs, offsets, counts, xbuf, Zbuf, n0, nn);
            k_gemm<<<(M + 63) / 64, 256, 0, stream>>>(Zbuf, Bfrag, out, n0 * 4, M);
        }
    } else {
        hipMemsetAsync(d_out, 0, (size_t)out_size * sizeof(float), stream);
        k_edge_atomic<<<(E + EBS - 1) / EBS, EBS, 0, stream>>>(
            edge_features, fc_w1, fc_b1, fc_w2, fc_b2, edge_src, edge_dst, xbuf, out, E);
    }

    // epilogue: per-node shuffle lin2 + self-connection (in place on out)
    k_node_out<<<(N + 3) / 4, 256, 0, stream>>>(sbuf, w2n_ws, out, N);
}

// Round 8
// 429.872 us; speedup vs baseline: 1.6375x; 1.0213x over previous
//
#include <hip/hip_runtime.h>
#include <math.h>

// Problem dims (fixed by reference)
#define CC 4
#define FE 32
#define HH 64
#define EBS 256
#define KEXT 544          // 512 + 32 (8 xbar cols + 24 zero pad), 17 K-steps of 32
#define ZSTRIDE 68        // uint4 per Z row (KEXT/8)

typedef __attribute__((ext_vector_type(8))) short bf16x8;
typedef __attribute__((ext_vector_type(4))) float f32x4;

// bf16 round-to-nearest-even pack
__device__ inline unsigned short f2bf(float f) {
    unsigned u = __float_as_uint(f);
    u += 0x7fffu + ((u >> 16) & 1u);
    return (unsigned short)(u >> 16);
}
__device__ inline float bf2f(unsigned short b) {
    return __uint_as_float(((unsigned)b) << 16);
}

// ---------------------------------------------------------------------------
// Node prep (one wave per node, shuffle-based, low-VGPR):
//   wbar1[i,j] = sum_a attr[a] W_lin1[i,a,j]      (lane = i*8+j, 16 FMA)
//   wbsc [i,j] = sum_a attr[a] W_sc  [i,a,j]
//   w2n  [o,p] = sum_a attr[a] W_lin2[o,a,p]  -> w2n_ws (scaled c_x/sqrt8)
//   x[c,j] = sum_i ni[c,i] wbar1[i,j]         -> xbuf
//   s[c,j] = c_s * sum_i ni[c,i] wbsc[i,j]    -> sbuf
// ---------------------------------------------------------------------------
__global__ __launch_bounds__(256) void k_nodeprep(
    const float* __restrict__ node_input, const float* __restrict__ node_attr,
    const float* __restrict__ W_lin1, const float* __restrict__ W_sc,
    const float* __restrict__ W_lin2,
    float* __restrict__ xbuf, float* __restrict__ sbuf,
    float* __restrict__ w2n_ws, int N)
{
    const float c_s = 0.3826834323650898f;
    const float c_x_scaled = 0.9238795325112867f * 0.35355339059327373f; // c_x/sqrt(8)
    int node = blockIdx.x * 4 + (threadIdx.x >> 6);
    int lane = threadIdx.x & 63;
    if (node >= N) return;

    float attr_own = (lane < 16) ? node_attr[(size_t)node * 16 + lane] : 0.f;
    float ni_own   = (lane < 32) ? node_input[(size_t)node * 32 + lane] : 0.f; // lane=c*8+i

    int iw = lane >> 3, jw = lane & 7;   // this lane's (i,j) / (o,p)
    float wb1 = 0.f, wbs = 0.f, w2n = 0.f;
    #pragma unroll
    for (int a = 0; a < 16; ++a) {
        float fa = __shfl(attr_own, a);
        int idx = (iw * 16 + a) * 8 + jw;
        wb1 += fa * W_lin1[idx];
        wbs += fa * W_sc[idx];
        w2n += fa * W_lin2[idx];
    }
    w2n_ws[(size_t)node * 64 + lane] = c_x_scaled * w2n;

    // x/s for lane<32 (c = lane>>3, j = lane&7); lanes>=32 compute duplicates
    int c_ = (lane >> 3) & 3, jo = lane & 7;
    float xo = 0.f, so = 0.f;
    #pragma unroll
    for (int i = 0; i < 8; ++i) {
        float niv = __shfl(ni_own, c_ * 8 + i);
        xo += niv * __shfl(wb1, i * 8 + jo);
        so += niv * __shfl(wbs, i * 8 + jo);
    }
    if (lane < 32) {
        xbuf[(size_t)node * 32 + lane] = xo;
        sbuf[(size_t)node * 32 + lane] = c_s * so;
    }
}

// ---------------------------------------------------------------------------
// CSR build over edge_dst
// ---------------------------------------------------------------------------
__global__ __launch_bounds__(256) void k_hist(
    const int* __restrict__ edge_dst, int* __restrict__ counts, int E)
{
    int e = blockIdx.x * 256 + threadIdx.x;
    if (e < E) atomicAdd(&counts[edge_dst[e]], 1);
}

// single-block shfl-based scan (16 waves of 64)
__global__ __launch_bounds__(1024) void k_scan(
    const int* __restrict__ counts, int* __restrict__ offsets,
    int* __restrict__ cursor, int N)
{
    __shared__ int wsum[16];
    __shared__ int wpre[16];
    __shared__ int s_tot;
    __shared__ int s_carry;
    int tid = threadIdx.x, wid = tid >> 6, lane = tid & 63;
    if (tid == 0) s_carry = 0;
    __syncthreads();
    for (int base = 0; base < N; base += 1024) {
        int idx = base + tid;
        int v = (idx < N) ? counts[idx] : 0;
        int x = v;
        #pragma unroll
        for (int s = 1; s < 64; s <<= 1) {
            int y = __shfl_up(x, s);
            if (lane >= s) x += y;
        }
        if (lane == 63) wsum[wid] = x;
        __syncthreads();
        if (wid == 0) {
            int wv = (lane < 16) ? wsum[lane] : 0;
            int wx = wv;
            #pragma unroll
            for (int s = 1; s < 16; s <<= 1) {
                int y = __shfl_up(wx, s);
                if (lane >= s) wx += y;
            }
            if (lane < 16) wpre[lane] = wx - wv;
            if (lane == 15) s_tot = wx;
        }
        __syncthreads();
        if (idx < N) {
            int excl = s_carry + wpre[wid] + (x - v);
            offsets[idx] = excl;
            cursor[idx] = excl;
        }
        __syncthreads();
        if (tid == 0) s_carry += s_tot;
    }
}

// fill permutation: esrc[pos] = {edge id, src} (one int2 per permuted slot)
__global__ __launch_bounds__(256) void k_fill(
    const int* __restrict__ edge_dst, const int* __restrict__ edge_src,
    int* __restrict__ cursor, int2* __restrict__ esrc, int E)
{
    int e = blockIdx.x * 256 + threadIdx.x;
    if (e < E) {
        int pos = atomicAdd(&cursor[edge_dst[e]], 1);
        int2 v; v.x = e; v.y = edge_src[e];
        esrc[pos] = v;
    }
}

// ---------------------------------------------------------------------------
// Pack W2 (+ b2 as K-rows 512..519, zeros 520..543) into MFMA B-frag order.
// ---------------------------------------------------------------------------
__global__ __launch_bounds__(256) void k_prep_bfrag(
    const float* __restrict__ fc_w2, const float* __restrict__ fc_b2,
    unsigned short* __restrict__ Bfrag)
{
    int t = blockIdx.x * 256 + threadIdx.x;
    if (t >= KEXT * 64) return;
    int kappa = t >> 6, nu = t & 63;
    int d = nu >> 3, o = nu & 7;
    float val;
    if (kappa < 512)      val = fc_w2[(size_t)(kappa >> 3) * 512 + d * 64 + (kappa & 7) * 8 + o];
    else if (kappa < 520) val = fc_b2[d * 64 + (kappa & 7) * 8 + o];
    else                  val = 0.f;
    int kk = kappa >> 5;
    int lane = ((kappa >> 3) & 3) * 16 + (nu & 15);
    int ct = nu >> 4;
    int j = kappa & 7;
    Bfrag[(size_t)((kk * 4 + ct) * 64 + lane) * 8 + j] = f2bf(val);
}

// ---------------------------------------------------------------------------
// H build in ORIGINAL edge order (fully coalesced stream):
//   H[e, k] = silu(ef[e,:] . W1[:,k] + b1[k]) as bf16
// ---------------------------------------------------------------------------
__global__ __launch_bounds__(256) void k_hsilu(
    const float* __restrict__ edge_features,
    const float* __restrict__ fc_w1, const float* __restrict__ fc_b1,
    unsigned short* __restrict__ H, int E)
{
    __shared__ float w1lds[FE * HH];
    __shared__ float b1lds[HH];
    int tid = threadIdx.x;
    #pragma unroll
    for (int it = 0; it < (FE * HH) / 256; ++it)
        w1lds[it * 256 + tid] = fc_w1[it * 256 + tid];
    if (tid < HH) b1lds[tid] = fc_b1[tid];
    __syncthreads();

    int e = blockIdx.x * 256 + tid;
    if (e >= E) return;

    float efv[FE];
    const float4* efp = reinterpret_cast<const float4*>(edge_features + (size_t)e * FE);
    #pragma unroll
    for (int q = 0; q < FE / 4; ++q) {
        float4 v = efp[q];
        efv[q * 4 + 0] = v.x; efv[q * 4 + 1] = v.y;
        efv[q * 4 + 2] = v.z; efv[q * 4 + 3] = v.w;
    }
    float h[HH];
    #pragma unroll
    for (int k = 0; k < HH; ++k) h[k] = b1lds[k];
    #pragma unroll
    for (int f = 0; f < FE; ++f) {
        float ev = efv[f];
        const float4* wp = reinterpret_cast<const float4*>(&w1lds[f * HH]);
        #pragma unroll
        for (int q = 0; q < HH / 4; ++q) {
            float4 w = wp[q];
            h[q * 4 + 0] += ev * w.x;
            h[q * 4 + 1] += ev * w.y;
            h[q * 4 + 2] += ev * w.z;
            h[q * 4 + 3] += ev * w.w;
        }
    }
    unsigned short* Hrow = H + (size_t)e * HH;
    #pragma unroll
    for (int q = 0; q < 8; ++q) {
        float s0 = h[q * 8 + 0], s1 = h[q * 8 + 1], s2 = h[q * 8 + 2], s3 = h[q * 8 + 3];
        float s4 = h[q * 8 + 4], s5 = h[q * 8 + 5], s6 = h[q * 8 + 6], s7 = h[q * 8 + 7];
        s0 /= (1.f + __expf(-s0)); s1 /= (1.f + __expf(-s1));
        s2 /= (1.f + __expf(-s2)); s3 /= (1.f + __expf(-s3));
        s4 /= (1.f + __expf(-s4)); s5 /= (1.f + __expf(-s5));
        s6 /= (1.f + __expf(-s6)); s7 /= (1.f + __expf(-s7));
        uint4 pk;
        pk.x = (unsigned)f2bf(s0) | ((unsigned)f2bf(s1) << 16);
        pk.y = (unsigned)f2bf(s2) | ((unsigned)f2bf(s3) << 16);
        pk.z = (unsigned)f2bf(s4) | ((unsigned)f2bf(s5) << 16);
        pk.w = (unsigned)f2bf(s6) | ((unsigned)f2bf(s7) << 16);
        reinterpret_cast<uint4*>(Hrow)[q] = pk;
    }
}

// ---------------------------------------------------------------------------
// Z build: one wave per node. lane k owns h[e,k].
// H is in original edge order; edge id + src arrive via esrc preload + shfl.
// Z row (KEXT cols): [0..511] = z, [512..519] = xbar (row's c), [520..543] = 0.
// ---------------------------------------------------------------------------
__global__ __launch_bounds__(256) void k_zbuild(
    const unsigned short* __restrict__ H, const int2* __restrict__ esrc,
    const int* __restrict__ offsets, const int* __restrict__ counts,
    const float* __restrict__ xin,
    unsigned short* __restrict__ Z,
    int n0, int nNodes)
{
    int node_l = blockIdx.x * 4 + (threadIdx.x >> 6);
    int lane = threadIdx.x & 63;
    if (node_l >= nNodes) return;
    int node = n0 + node_l;
    int off = offsets[node], cnt = counts[node];

    float z[CC][8];
    #pragma unroll
    for (int c = 0; c < CC; ++c)
        #pragma unroll
        for (int i = 0; i < 8; ++i) z[c][i] = 0.f;
    float xsown = 0.f;

    for (int base = 0; base < cnt; base += 64) {
        int m = (cnt - base < 64) ? (cnt - base) : 64;
        int2 ej = (lane < m) ? esrc[off + base + lane] : make_int2(0, 0);
        #pragma unroll 2
        for (int j = 0; j < m; ++j) {
            int e   = __shfl(ej.x, j);
            int src = __shfl(ej.y, j);
            float hk = bf2f(H[(size_t)e * HH + lane]);
            const float4* xp = reinterpret_cast<const float4*>(xin + (size_t)src * 32);
            float xs[32];
            #pragma unroll
            for (int q = 0; q < 8; ++q) {
                float4 v = xp[q];
                xs[q * 4 + 0] = v.x; xs[q * 4 + 1] = v.y;
                xs[q * 4 + 2] = v.z; xs[q * 4 + 3] = v.w;
            }
            #pragma unroll
            for (int c = 0; c < CC; ++c)
                #pragma unroll
                for (int i = 0; i < 8; ++i)
                    z[c][i] += hk * xs[c * 8 + i];
            xsown += xin[(size_t)src * 32 + (lane & 31)];
        }
    }

    uint4* Zu = reinterpret_cast<uint4*>(Z);
    #pragma unroll
    for (int c = 0; c < CC; ++c) {
        uint4 pk;
        pk.x = (unsigned)f2bf(z[c][0]) | ((unsigned)f2bf(z[c][1]) << 16);
        pk.y = (unsigned)f2bf(z[c][2]) | ((unsigned)f2bf(z[c][3]) << 16);
        pk.z = (unsigned)f2bf(z[c][4]) | ((unsigned)f2bf(z[c][5]) << 16);
        pk.w = (unsigned)f2bf(z[c][6]) | ((unsigned)f2bf(z[c][7]) << 16);
        Zu[(size_t)(node_l * 4 + c) * ZSTRIDE + lane] = pk;
    }
    // xbar columns (kappa 512..519): row c gets xsown from lanes c*8..c*8+7
    float xb[8];
    #pragma unroll
    for (int i = 0; i < 8; ++i) xb[i] = __shfl(xsown, (lane & 3) * 8 + i);
    int r4 = node_l * 4;
    if (lane < 4) {
        uint4 pk;
        pk.x = (unsigned)f2bf(xb[0]) | ((unsigned)f2bf(xb[1]) << 16);
        pk.y = (unsigned)f2bf(xb[2]) | ((unsigned)f2bf(xb[3]) << 16);
        pk.z = (unsigned)f2bf(xb[4]) | ((unsigned)f2bf(xb[5]) << 16);
        pk.w = (unsigned)f2bf(xb[6]) | ((unsigned)f2bf(xb[7]) << 16);
        Zu[(size_t)(r4 + lane) * ZSTRIDE + 64] = pk;
    } else if (lane < 16) {
        int j = lane - 4;   // 12 zero-pad uint4s: rows 0..3 x slots 65..67
        uint4 zz; zz.x = 0u; zz.y = 0u; zz.z = 0u; zz.w = 0u;
        Zu[(size_t)(r4 + (j & 3)) * ZSTRIDE + 65 + (j >> 2)] = zz;
    }
}

// ---------------------------------------------------------------------------
// GEMM: agg[M,64] = Z[M,KEXT] @ B[KEXT,64], bf16 MFMA 16x16x32, fp32 out.
// kk 0..15 from LDS (64 KB cap); kk=16 (bias block) B kept in registers.
// ---------------------------------------------------------------------------
__global__ __launch_bounds__(256) void k_gemm(
    const unsigned short* __restrict__ Z, const unsigned short* __restrict__ Bfrag,
    float* __restrict__ out, int row_base, int M)
{
    __shared__ short blds[32768];
    int tid = threadIdx.x;
    #pragma unroll
    for (int it = 0; it < 16; ++it) {
        int idx = it * 256 + tid;
        reinterpret_cast<uint4*>(blds)[idx] = reinterpret_cast<const uint4*>(Bfrag)[idx];
    }
    __syncthreads();

    int w = tid >> 6, l = tid & 63;
    int rbase = blockIdx.x * 64 + w * 16;
    int arow = rbase + (l & 15);
    if (arow >= M) arow = M - 1;

    // bias-block B fragments (kk=16) from global
    bf16x8 bx[4];
    #pragma unroll
    for (int ct = 0; ct < 4; ++ct) {
        uint4 bv = reinterpret_cast<const uint4*>(Bfrag)[(64 + ct) * 64 + l];
        bx[ct] = *reinterpret_cast<bf16x8*>(&bv);
    }

    f32x4 acc[4];
    #pragma unroll
    for (int ct = 0; ct < 4; ++ct) acc[ct] = (f32x4){0.f, 0.f, 0.f, 0.f};

    #pragma unroll
    for (int kk = 0; kk < 16; ++kk) {
        uint4 av = reinterpret_cast<const uint4*>(Z)[(size_t)arow * ZSTRIDE + kk * 4 + (l >> 4)];
        bf16x8 a = *reinterpret_cast<bf16x8*>(&av);
        #pragma unroll
        for (int ct = 0; ct < 4; ++ct) {
            bf16x8 b = *reinterpret_cast<const bf16x8*>(&blds[(size_t)((kk * 4 + ct) * 64 + l) * 8]);
            acc[ct] = __builtin_amdgcn_mfma_f32_16x16x32_bf16(a, b, acc[ct], 0, 0, 0);
        }
    }
    {   // bias K-step
        uint4 av = reinterpret_cast<const uint4*>(Z)[(size_t)arow * ZSTRIDE + 64 + (l >> 4)];
        bf16x8 a = *reinterpret_cast<bf16x8*>(&av);
        #pragma unroll
        for (int ct = 0; ct < 4; ++ct)
            acc[ct] = __builtin_amdgcn_mfma_f32_16x16x32_bf16(a, bx[ct], acc[ct], 0, 0, 0);
    }

    #pragma unroll
    for (int ct = 0; ct < 4; ++ct) {
        #pragma unroll
        for (int v = 0; v < 4; ++v) {
            int r = rbase + (l >> 4) * 4 + v;
            if (r < M)
                out[(size_t)(row_base + r) * 64 + ct * 16 + (l & 15)] = acc[ct][v];
        }
    }
}

// ---------------------------------------------------------------------------
// Kernel C: one wave per node, pure-register shuffle epilogue.
//   out[n,c,d,p] = sbuf[n,c,p] + sum_o agg[n,c,d,o] * w2n_ws[n,o,p]
// ---------------------------------------------------------------------------
__global__ __launch_bounds__(256) void k_node_out(
    const float* __restrict__ sbuf, const float* __restrict__ w2n_ws,
    float* __restrict__ out, int N)
{
    int node = blockIdx.x * 4 + (threadIdx.x >> 6);
    int lane = threadIdx.x & 63;
    if (node >= N) return;
    int d = lane >> 3, p = lane & 7;

    float w2 = w2n_ws[(size_t)node * 64 + lane];            // w2n[o=lane>>3, p=lane&7]
    float s_own = sbuf[(size_t)node * 32 + (lane & 31)];    // s[c=lane>>3&3, o=lane&7]

    float w2sh[8];
    #pragma unroll
    for (int o = 0; o < 8; ++o) w2sh[o] = __shfl(w2, o * 8 + p);

    float* rowp = out + (size_t)node * 256;
    #pragma unroll
    for (int c = 0; c < CC; ++c) {
        float a_own = rowp[c * 64 + lane];                  // agg[c, d=lane>>3, o=lane&7]
        float res = 0.f;
        #pragma unroll
        for (int o = 0; o < 8; ++o)
            res += __shfl(a_own, d * 8 + o) * w2sh[o];
        float sval = __shfl(s_own, c * 8 + p);
        rowp[c * 64 + lane] = sval + res;
    }
}

// ---------------------------------------------------------------------------
// Fallback edge kernel (global atomics) — only if ws too small.
// ---------------------------------------------------------------------------
__global__ __launch_bounds__(EBS) void k_edge_atomic(
    const float* __restrict__ edge_features,
    const float* __restrict__ fc_w1, const float* __restrict__ fc_b1,
    const float* __restrict__ fc_w2, const float* __restrict__ fc_b2,
    const int* __restrict__ edge_src, const int* __restrict__ edge_dst,
    const float* __restrict__ xin, float* __restrict__ agg, int E)
{
    __shared__ float hlds[HH * EBS];
    int e = blockIdx.x * EBS + threadIdx.x;
    if (e >= E) return;
    float h[HH];
    #pragma unroll
    for (int k = 0; k < HH; ++k) h[k] = fc_b1[k];
    const float4* efp = reinterpret_cast<const float4*>(edge_features + (size_t)e * FE);
    #pragma unroll
    for (int fq = 0; fq < FE / 4; ++fq) {
        float4 efv = efp[fq];
        float ev[4] = {efv.x, efv.y, efv.z, efv.w};
        #pragma unroll
        for (int fs = 0; fs < 4; ++fs) {
            float evv = ev[fs];
            const float4* w1p = reinterpret_cast<const float4*>(fc_w1 + (fq * 4 + fs) * HH);
            #pragma unroll
            for (int q = 0; q < HH / 4; ++q) {
                float4 w = w1p[q];
                h[q * 4 + 0] += evv * w.x;
                h[q * 4 + 1] += evv * w.y;
                h[q * 4 + 2] += evv * w.z;
                h[q * 4 + 3] += evv * w.w;
            }
        }
    }
    #pragma unroll
    for (int k = 0; k < HH; ++k) {
        float v = h[k];
        hlds[k * EBS + threadIdx.x] = v / (1.f + __expf(-v));
    }
    int src = edge_src[e], dst = edge_dst[e];
    float xs[32];
    const float4* xp = reinterpret_cast<const float4*>(xin + (size_t)src * 32);
    #pragma unroll
    for (int q = 0; q < 8; ++q) {
        float4 v = xp[q];
        xs[q * 4 + 0] = v.x; xs[q * 4 + 1] = v.y;
        xs[q * 4 + 2] = v.z; xs[q * 4 + 3] = v.w;
    }
    float* outp = agg + (size_t)dst * 256;
    #pragma unroll 1
    for (int d = 0; d < 8; ++d) {
        float t[64];
        const float4* b2p = reinterpret_cast<const float4*>(fc_b2 + d * 64);
        #pragma unroll
        for (int q = 0; q < 16; ++q) {
            float4 v = b2p[q];
            t[q * 4 + 0] = v.x; t[q * 4 + 1] = v.y;
            t[q * 4 + 2] = v.z; t[q * 4 + 3] = v.w;
        }
        for (int k = 0; k < HH; ++k) {
            float hv = hlds[k * EBS + threadIdx.x];
            const float4* wp = reinterpret_cast<const float4*>(fc_w2 + (size_t)k * 512 + d * 64);
            #pragma unroll
            for (int q = 0; q < 16; ++q) {
                float4 w = wp[q];
                t[q * 4 + 0] += hv * w.x;
                t[q * 4 + 1] += hv * w.y;
                t[q * 4 + 2] += hv * w.z;
                t[q * 4 + 3] += hv * w.w;
            }
        }
        #pragma unroll
        for (int c = 0; c < CC; ++c) {
            #pragma unroll
            for (int o = 0; o < 8; ++o) {
                float acc = 0.f;
                #pragma unroll
                for (int i = 0; i < 8; ++i) acc += xs[c * 8 + i] * t[i * 8 + o];
                atomicAdd(outp + c * 64 + d * 8 + o, acc);
            }
        }
    }
}

// ---------------------------------------------------------------------------
extern "C" void kernel_launch(void* const* d_in, const int* in_sizes, int n_in,
                              void* d_out, int out_size, void* d_ws, size_t ws_size,
                              hipStream_t stream)
{
    const float* node_input    = (const float*)d_in[0];
    const float* node_attr     = (const float*)d_in[1];
    const float* edge_features = (const float*)d_in[2];
    const float* W_sc          = (const float*)d_in[3];
    const float* W_lin1        = (const float*)d_in[4];
    const float* W_lin2        = (const float*)d_in[5];
    const float* fc_w1         = (const float*)d_in[6];
    const float* fc_b1         = (const float*)d_in[7];
    const float* fc_w2         = (const float*)d_in[8];
    const float* fc_b2         = (const float*)d_in[9];
    const int*   edge_src      = (const int*)d_in[10];
    const int*   edge_dst      = (const int*)d_in[11];

    const int N = in_sizes[1] / 16;
    const int E = in_sizes[10];

    char* ws = (char*)d_ws;
    size_t off = 0;
    auto take = [&](size_t bytes) { char* p = ws + off; off += (bytes + 15) & ~(size_t)15; return p; };
    float* xbuf            = (float*)take((size_t)N * 32 * sizeof(float));
    float* sbuf            = (float*)take((size_t)N * 32 * sizeof(float));
    float* w2n_ws          = (float*)take((size_t)N * 64 * sizeof(float));
    int*   counts          = (int*)take((size_t)N * sizeof(int));
    int*   offsets         = (int*)take((size_t)N * sizeof(int));
    int*   cursor          = (int*)take((size_t)N * sizeof(int));
    int2*  esrc            = (int2*)take((size_t)E * sizeof(int2));
    unsigned short* Bfrag  = (unsigned short*)take((size_t)17 * 4 * 64 * 8 * sizeof(unsigned short));
    unsigned short* Hbuf   = (unsigned short*)take((size_t)E * HH * sizeof(unsigned short));
    size_t fixed_off = off;
    unsigned short* Zbuf   = (unsigned short*)(ws + fixed_off);

    long long avail = (long long)ws_size - (long long)fixed_off;
    int npp = (avail > 0) ? (int)(avail / (4 * KEXT * 2)) : 0;   // bytes per node
    bool fast = (npp >= 64);

    float* out = (float*)d_out;

    // node prep: x, c_s*s, w2n (one wave per node, shuffle-based)
    k_nodeprep<<<(N + 3) / 4, 256, 0, stream>>>(
        node_input, node_attr, W_lin1, W_sc, W_lin2, xbuf, sbuf, w2n_ws, N);

    if (fast) {
        if (npp > N) npp = N;
        int passes = (N + npp - 1) / npp;
        npp = (N + passes - 1) / passes;

        // CSR over edge_dst ({e,src} gather)
        hipMemsetAsync(counts, 0, (size_t)N * sizeof(int), stream);
        k_hist<<<(E + 255) / 256, 256, 0, stream>>>(edge_dst, counts, E);
        k_scan<<<1, 1024, 0, stream>>>(counts, offsets, cursor, N);
        k_fill<<<(E + 255) / 256, 256, 0, stream>>>(edge_dst, edge_src, cursor, esrc, E);
        // radial layer-1 for all edges, ORIGINAL order (coalesced stream)
        k_hsilu<<<(E + 255) / 256, 256, 0, stream>>>(edge_features, fc_w1, fc_b1, Hbuf, E);
        // pack W2+b2 into B-fragment order
        k_prep_bfrag<<<(KEXT * 64 + 255) / 256, 256, 0, stream>>>(fc_w2, fc_b2, Bfrag);

        for (int p = 0; p < passes; ++p) {
            int n0 = p * npp;
            int nn = (n0 + npp <= N) ? npp : (N - n0);
            int M = nn * 4;
            k_zbuild<<<(nn + 3) / 4, 256, 0, stream>>>(
                Hbuf, esrc, offsets, counts, xbuf, Zbuf, n0, nn);
            k_gemm<<<(M + 63) / 64, 256, 0, stream>>>(Zbuf, Bfrag, out, n0 * 4, M);
        }
    } else {
        hipMemsetAsync(d_out, 0, (size_t)out_size * sizeof(float), stream);
        k_edge_atomic<<<(E + EBS - 1) / EBS, EBS, 0, stream>>>(
            edge_features, fc_w1, fc_b1, fc_w2, fc_b2, edge_src, edge_dst, xbuf, out, E);
    }

    // epilogue: per-node shuffle lin2 + self-connection (in place on out)
    k_node_out<<<(N + 3) / 4, 256, 0, stream>>>(sbuf, w2n_ws, out, N);
}

// Round 9
// 386.428 us; speedup vs baseline: 1.8216x; 1.1124x over previous
//
#include <hip/hip_runtime.h>
#include <math.h>

// Problem dims (fixed by reference)
#define CC 4
#define FE 32
#define HH 64
#define EBS 256
#define KEXT 544          // 512 + 32 (8 xbar cols + 24 zero pad), 17 K-steps of 32
#define ZSTRIDE 68        // uint4 per Z row (KEXT/8)

typedef __attribute__((ext_vector_type(8))) short bf16x8;
typedef __attribute__((ext_vector_type(4))) float f32x4;

// bf16 round-to-nearest-even pack
__device__ inline unsigned short f2bf(float f) {
    unsigned u = __float_as_uint(f);
    u += 0x7fffu + ((u >> 16) & 1u);
    return (unsigned short)(u >> 16);
}
__device__ inline float bf2f(unsigned short b) {
    return __uint_as_float(((unsigned)b) << 16);
}

// ---------------------------------------------------------------------------
// Node prep (one wave per node, shuffle-based, low-VGPR)
// ---------------------------------------------------------------------------
__global__ __launch_bounds__(256) void k_nodeprep(
    const float* __restrict__ node_input, const float* __restrict__ node_attr,
    const float* __restrict__ W_lin1, const float* __restrict__ W_sc,
    const float* __restrict__ W_lin2,
    float* __restrict__ xbuf, float* __restrict__ sbuf,
    float* __restrict__ w2n_ws, int N)
{
    const float c_s = 0.3826834323650898f;
    const float c_x_scaled = 0.9238795325112867f * 0.35355339059327373f; // c_x/sqrt(8)
    int node = blockIdx.x * 4 + (threadIdx.x >> 6);
    int lane = threadIdx.x & 63;
    if (node >= N) return;

    float attr_own = (lane < 16) ? node_attr[(size_t)node * 16 + lane] : 0.f;
    float ni_own   = (lane < 32) ? node_input[(size_t)node * 32 + lane] : 0.f; // lane=c*8+i

    int iw = lane >> 3, jw = lane & 7;   // this lane's (i,j) / (o,p)
    float wb1 = 0.f, wbs = 0.f, w2n = 0.f;
    #pragma unroll
    for (int a = 0; a < 16; ++a) {
        float fa = __shfl(attr_own, a);
        int idx = (iw * 16 + a) * 8 + jw;
        wb1 += fa * W_lin1[idx];
        wbs += fa * W_sc[idx];
        w2n += fa * W_lin2[idx];
    }
    w2n_ws[(size_t)node * 64 + lane] = c_x_scaled * w2n;

    int c_ = (lane >> 3) & 3, jo = lane & 7;
    float xo = 0.f, so = 0.f;
    #pragma unroll
    for (int i = 0; i < 8; ++i) {
        float niv = __shfl(ni_own, c_ * 8 + i);
        xo += niv * __shfl(wb1, i * 8 + jo);
        so += niv * __shfl(wbs, i * 8 + jo);
    }
    if (lane < 32) {
        xbuf[(size_t)node * 32 + lane] = xo;
        sbuf[(size_t)node * 32 + lane] = c_s * so;
    }
}

// ---------------------------------------------------------------------------
// CSR build over edge_dst
// ---------------------------------------------------------------------------
__global__ __launch_bounds__(256) void k_hist(
    const int* __restrict__ edge_dst, int* __restrict__ counts, int E)
{
    int e = blockIdx.x * 256 + threadIdx.x;
    if (e < E) atomicAdd(&counts[edge_dst[e]], 1);
}

// single-block shfl-based scan (16 waves of 64)
__global__ __launch_bounds__(1024) void k_scan(
    const int* __restrict__ counts, int* __restrict__ offsets,
    int* __restrict__ cursor, int N)
{
    __shared__ int wsum[16];
    __shared__ int wpre[16];
    __shared__ int s_tot;
    __shared__ int s_carry;
    int tid = threadIdx.x, wid = tid >> 6, lane = tid & 63;
    if (tid == 0) s_carry = 0;
    __syncthreads();
    for (int base = 0; base < N; base += 1024) {
        int idx = base + tid;
        int v = (idx < N) ? counts[idx] : 0;
        int x = v;
        #pragma unroll
        for (int s = 1; s < 64; s <<= 1) {
            int y = __shfl_up(x, s);
            if (lane >= s) x += y;
        }
        if (lane == 63) wsum[wid] = x;
        __syncthreads();
        if (wid == 0) {
            int wv = (lane < 16) ? wsum[lane] : 0;
            int wx = wv;
            #pragma unroll
            for (int s = 1; s < 16; s <<= 1) {
                int y = __shfl_up(wx, s);
                if (lane >= s) wx += y;
            }
            if (lane < 16) wpre[lane] = wx - wv;
            if (lane == 15) s_tot = wx;
        }
        __syncthreads();
        if (idx < N) {
            int excl = s_carry + wpre[wid] + (x - v);
            offsets[idx] = excl;
            cursor[idx] = excl;
        }
        __syncthreads();
        if (tid == 0) s_carry += s_tot;
    }
}

// fill permutation: esrc[pos] = {edge id, src}
__global__ __launch_bounds__(256) void k_fill(
    const int* __restrict__ edge_dst, const int* __restrict__ edge_src,
    int* __restrict__ cursor, int2* __restrict__ esrc, int E)
{
    int e = blockIdx.x * 256 + threadIdx.x;
    if (e < E) {
        int pos = atomicAdd(&cursor[edge_dst[e]], 1);
        int2 v; v.x = e; v.y = edge_src[e];
        esrc[pos] = v;
    }
}

// ---------------------------------------------------------------------------
// Pack W2 (+ b2 as K-rows 512..519, zeros 520..543) into MFMA B-frag order.
// ---------------------------------------------------------------------------
__global__ __launch_bounds__(256) void k_prep_bfrag(
    const float* __restrict__ fc_w2, const float* __restrict__ fc_b2,
    unsigned short* __restrict__ Bfrag)
{
    int t = blockIdx.x * 256 + threadIdx.x;
    if (t >= KEXT * 64) return;
    int kappa = t >> 6, nu = t & 63;
    int d = nu >> 3, o = nu & 7;
    float val;
    if (kappa < 512)      val = fc_w2[(size_t)(kappa >> 3) * 512 + d * 64 + (kappa & 7) * 8 + o];
    else if (kappa < 520) val = fc_b2[d * 64 + (kappa & 7) * 8 + o];
    else                  val = 0.f;
    int kk = kappa >> 5;
    int lane = ((kappa >> 3) & 3) * 16 + (nu & 15);
    int ct = nu >> 4;
    int j = kappa & 7;
    Bfrag[(size_t)((kk * 4 + ct) * 64 + lane) * 8 + j] = f2bf(val);
}

// ---------------------------------------------------------------------------
// Pack W1 [32,64] into MFMA B-frag order (one K-step):
//   Bfrag1[(ct*64 + l)*8 + j] = bf16(W1[k, n]), k=(l>>4)*8+j, n=ct*16+(l&15)
// ---------------------------------------------------------------------------
__global__ __launch_bounds__(256) void k_prep_bfrag1(
    const float* __restrict__ fc_w1, unsigned short* __restrict__ Bfrag1)
{
    int t = blockIdx.x * 256 + threadIdx.x;   // 2048 threads
    if (t >= 4 * 64 * 8) return;
    int j = t & 7, l = (t >> 3) & 63, ct = t >> 9;
    int k = (l >> 4) * 8 + j;
    int n = ct * 16 + (l & 15);
    Bfrag1[t] = f2bf(fc_w1[(size_t)k * HH + n]);
}

// ---------------------------------------------------------------------------
// H build via MFMA (original edge order, no LDS):
//   H[e, n] = silu(ef[e,:] @ W1[:,n] + b1[n]) as bf16
// One wave = 16 edges: A frag from ef (coalesced 32B/lane), B in regs, 4 MFMA.
// ---------------------------------------------------------------------------
__global__ __launch_bounds__(256) void k_hsilu(
    const float* __restrict__ edge_features,
    const unsigned short* __restrict__ Bfrag1, const float* __restrict__ fc_b1,
    unsigned short* __restrict__ H, int E)
{
    int wid = threadIdx.x >> 6, lane = threadIdx.x & 63;
    int e0 = (blockIdx.x * 4 + wid) * 16;
    if (e0 >= E) return;

    // B fragments (register-resident, 4 x uint4)
    bf16x8 b[4];
    #pragma unroll
    for (int ct = 0; ct < 4; ++ct) {
        uint4 bv = reinterpret_cast<const uint4*>(Bfrag1)[ct * 64 + lane];
        b[ct] = *reinterpret_cast<bf16x8*>(&bv);
    }
    // bias for this lane's output column (same for all 4 rows)
    float bias[4];
    #pragma unroll
    for (int ct = 0; ct < 4; ++ct) bias[ct] = fc_b1[ct * 16 + (lane & 15)];

    // A fragment: row = e0 + (l&15), k = (l>>4)*8 + j  (32B contiguous fp32)
    int row = e0 + (lane & 15);
    if (row >= E) row = E - 1;
    const float4* ap = reinterpret_cast<const float4*>(
        edge_features + (size_t)row * FE + (lane >> 4) * 8);
    float4 a0 = ap[0], a1 = ap[1];
    unsigned au[4];
    au[0] = (unsigned)f2bf(a0.x) | ((unsigned)f2bf(a0.y) << 16);
    au[1] = (unsigned)f2bf(a0.z) | ((unsigned)f2bf(a0.w) << 16);
    au[2] = (unsigned)f2bf(a1.x) | ((unsigned)f2bf(a1.y) << 16);
    au[3] = (unsigned)f2bf(a1.z) | ((unsigned)f2bf(a1.w) << 16);
    bf16x8 a = *reinterpret_cast<bf16x8*>(au);

    f32x4 acc[4];
    #pragma unroll
    for (int ct = 0; ct < 4; ++ct) {
        acc[ct] = (f32x4){0.f, 0.f, 0.f, 0.f};
        acc[ct] = __builtin_amdgcn_mfma_f32_16x16x32_bf16(a, b[ct], acc[ct], 0, 0, 0);
    }

    // silu + store: C row = e0 + (l>>4)*4 + v, col = ct*16 + (l&15)
    #pragma unroll
    for (int ct = 0; ct < 4; ++ct) {
        #pragma unroll
        for (int v = 0; v < 4; ++v) {
            int r = e0 + (lane >> 4) * 4 + v;
            if (r < E) {
                float x = acc[ct][v] + bias[ct];
                float s = x / (1.f + __expf(-x));
                H[(size_t)r * HH + ct * 16 + (lane & 15)] = f2bf(s);
            }
        }
    }
}

// ---------------------------------------------------------------------------
// Z build: one wave per node. lane k owns h[e,k].
// ---------------------------------------------------------------------------
__global__ __launch_bounds__(256) void k_zbuild(
    const unsigned short* __restrict__ H, const int2* __restrict__ esrc,
    const int* __restrict__ offsets, const int* __restrict__ counts,
    const float* __restrict__ xin,
    unsigned short* __restrict__ Z,
    int n0, int nNodes)
{
    int node_l = blockIdx.x * 4 + (threadIdx.x >> 6);
    int lane = threadIdx.x & 63;
    if (node_l >= nNodes) return;
    int node = n0 + node_l;
    int off = offsets[node], cnt = counts[node];

    float z[CC][8];
    #pragma unroll
    for (int c = 0; c < CC; ++c)
        #pragma unroll
        for (int i = 0; i < 8; ++i) z[c][i] = 0.f;
    float xsown = 0.f;

    for (int base = 0; base < cnt; base += 64) {
        int m = (cnt - base < 64) ? (cnt - base) : 64;
        int2 ej = (lane < m) ? esrc[off + base + lane] : make_int2(0, 0);
        #pragma unroll 2
        for (int j = 0; j < m; ++j) {
            int e   = __shfl(ej.x, j);
            int src = __shfl(ej.y, j);
            float hk = bf2f(H[(size_t)e * HH + lane]);
            const float4* xp = reinterpret_cast<const float4*>(xin + (size_t)src * 32);
            float xs[32];
            #pragma unroll
            for (int q = 0; q < 8; ++q) {
                float4 v = xp[q];
                xs[q * 4 + 0] = v.x; xs[q * 4 + 1] = v.y;
                xs[q * 4 + 2] = v.z; xs[q * 4 + 3] = v.w;
            }
            #pragma unroll
            for (int c = 0; c < CC; ++c)
                #pragma unroll
                for (int i = 0; i < 8; ++i)
                    z[c][i] += hk * xs[c * 8 + i];
            xsown += xin[(size_t)src * 32 + (lane & 31)];
        }
    }

    uint4* Zu = reinterpret_cast<uint4*>(Z);
    #pragma unroll
    for (int c = 0; c < CC; ++c) {
        uint4 pk;
        pk.x = (unsigned)f2bf(z[c][0]) | ((unsigned)f2bf(z[c][1]) << 16);
        pk.y = (unsigned)f2bf(z[c][2]) | ((unsigned)f2bf(z[c][3]) << 16);
        pk.z = (unsigned)f2bf(z[c][4]) | ((unsigned)f2bf(z[c][5]) << 16);
        pk.w = (unsigned)f2bf(z[c][6]) | ((unsigned)f2bf(z[c][7]) << 16);
        Zu[(size_t)(node_l * 4 + c) * ZSTRIDE + lane] = pk;
    }
    float xb[8];
    #pragma unroll
    for (int i = 0; i < 8; ++i) xb[i] = __shfl(xsown, (lane & 3) * 8 + i);
    int r4 = node_l * 4;
    if (lane < 4) {
        uint4 pk;
        pk.x = (unsigned)f2bf(xb[0]) | ((unsigned)f2bf(xb[1]) << 16);
        pk.y = (unsigned)f2bf(xb[2]) | ((unsigned)f2bf(xb[3]) << 16);
        pk.z = (unsigned)f2bf(xb[4]) | ((unsigned)f2bf(xb[5]) << 16);
        pk.w = (unsigned)f2bf(xb[6]) | ((unsigned)f2bf(xb[7]) << 16);
        Zu[(size_t)(r4 + lane) * ZSTRIDE + 64] = pk;
    } else if (lane < 16) {
        int j = lane - 4;
        uint4 zz; zz.x = 0u; zz.y = 0u; zz.z = 0u; zz.w = 0u;
        Zu[(size_t)(r4 + (j & 3)) * ZSTRIDE + 65 + (j >> 2)] = zz;
    }
}

// ---------------------------------------------------------------------------
// GEMM: agg[M,64] = Z[M,KEXT] @ B[KEXT,64], bf16 MFMA 16x16x32, fp32 out.
// ---------------------------------------------------------------------------
__global__ __launch_bounds__(256) void k_gemm(
    const unsigned short* __restrict__ Z, const unsigned short* __restrict__ Bfrag,
    float* __restrict__ out, int row_base, int M)
{
    __shared__ short blds[32768];
    int tid = threadIdx.x;
    #pragma unroll
    for (int it = 0; it < 16; ++it) {
        int idx = it * 256 + tid;
        reinterpret_cast<uint4*>(blds)[idx] = reinterpret_cast<const uint4*>(Bfrag)[idx];
    }
    __syncthreads();

    int w = tid >> 6, l = tid & 63;
    int rbase = blockIdx.x * 64 + w * 16;
    int arow = rbase + (l & 15);
    if (arow >= M) arow = M - 1;

    bf16x8 bx[4];
    #pragma unroll
    for (int ct = 0; ct < 4; ++ct) {
        uint4 bv = reinterpret_cast<const uint4*>(Bfrag)[(64 + ct) * 64 + l];
        bx[ct] = *reinterpret_cast<bf16x8*>(&bv);
    }

    f32x4 acc[4];
    #pragma unroll
    for (int ct = 0; ct < 4; ++ct) acc[ct] = (f32x4){0.f, 0.f, 0.f, 0.f};

    #pragma unroll
    for (int kk = 0; kk < 16; ++kk) {
        uint4 av = reinterpret_cast<const uint4*>(Z)[(size_t)arow * ZSTRIDE + kk * 4 + (l >> 4)];
        bf16x8 a = *reinterpret_cast<bf16x8*>(&av);
        #pragma unroll
        for (int ct = 0; ct < 4; ++ct) {
            bf16x8 b = *reinterpret_cast<const bf16x8*>(&blds[(size_t)((kk * 4 + ct) * 64 + l) * 8]);
            acc[ct] = __builtin_amdgcn_mfma_f32_16x16x32_bf16(a, b, acc[ct], 0, 0, 0);
        }
    }
    {   // bias K-step
        uint4 av = reinterpret_cast<const uint4*>(Z)[(size_t)arow * ZSTRIDE + 64 + (l >> 4)];
        bf16x8 a = *reinterpret_cast<bf16x8*>(&av);
        #pragma unroll
        for (int ct = 0; ct < 4; ++ct)
            acc[ct] = __builtin_amdgcn_mfma_f32_16x16x32_bf16(a, bx[ct], acc[ct], 0, 0, 0);
    }

    #pragma unroll
    for (int ct = 0; ct < 4; ++ct) {
        #pragma unroll
        for (int v = 0; v < 4; ++v) {
            int r = rbase + (l >> 4) * 4 + v;
            if (r < M)
                out[(size_t)(row_base + r) * 64 + ct * 16 + (l & 15)] = acc[ct][v];
        }
    }
}

// ---------------------------------------------------------------------------
// Kernel C: one wave per node, pure-register shuffle epilogue.
// ---------------------------------------------------------------------------
__global__ __launch_bounds__(256) void k_node_out(
    const float* __restrict__ sbuf, const float* __restrict__ w2n_ws,
    float* __restrict__ out, int N)
{
    int node = blockIdx.x * 4 + (threadIdx.x >> 6);
    int lane = threadIdx.x & 63;
    if (node >= N) return;
    int d = lane >> 3, p = lane & 7;

    float w2 = w2n_ws[(size_t)node * 64 + lane];
    float s_own = sbuf[(size_t)node * 32 + (lane & 31)];

    float w2sh[8];
    #pragma unroll
    for (int o = 0; o < 8; ++o) w2sh[o] = __shfl(w2, o * 8 + p);

    float* rowp = out + (size_t)node * 256;
    #pragma unroll
    for (int c = 0; c < CC; ++c) {
        float a_own = rowp[c * 64 + lane];
        float res = 0.f;
        #pragma unroll
        for (int o = 0; o < 8; ++o)
            res += __shfl(a_own, d * 8 + o) * w2sh[o];
        float sval = __shfl(s_own, c * 8 + p);
        rowp[c * 64 + lane] = sval + res;
    }
}

// ---------------------------------------------------------------------------
// Fallback edge kernel (global atomics) — only if ws too small.
// ---------------------------------------------------------------------------
__global__ __launch_bounds__(EBS) void k_edge_atomic(
    const float* __restrict__ edge_features,
    const float* __restrict__ fc_w1, const float* __restrict__ fc_b1,
    const float* __restrict__ fc_w2, const float* __restrict__ fc_b2,
    const int* __restrict__ edge_src, const int* __restrict__ edge_dst,
    const float* __restrict__ xin, float* __restrict__ agg, int E)
{
    __shared__ float hlds[HH * EBS];
    int e = blockIdx.x * EBS + threadIdx.x;
    if (e >= E) return;
    float h[HH];
    #pragma unroll
    for (int k = 0; k < HH; ++k) h[k] = fc_b1[k];
    const float4* efp = reinterpret_cast<const float4*>(edge_features + (size_t)e * FE);
    #pragma unroll
    for (int fq = 0; fq < FE / 4; ++fq) {
        float4 efv = efp[fq];
        float ev[4] = {efv.x, efv.y, efv.z, efv.w};
        #pragma unroll
        for (int fs = 0; fs < 4; ++fs) {
            float evv = ev[fs];
            const float4* w1p = reinterpret_cast<const float4*>(fc_w1 + (fq * 4 + fs) * HH);
            #pragma unroll
            for (int q = 0; q < HH / 4; ++q) {
                float4 w = w1p[q];
                h[q * 4 + 0] += evv * w.x;
                h[q * 4 + 1] += evv * w.y;
                h[q * 4 + 2] += evv * w.z;
                h[q * 4 + 3] += evv * w.w;
            }
        }
    }
    #pragma unroll
    for (int k = 0; k < HH; ++k) {
        float v = h[k];
        hlds[k * EBS + threadIdx.x] = v / (1.f + __expf(-v));
    }
    int src = edge_src[e], dst = edge_dst[e];
    float xs[32];
    const float4* xp = reinterpret_cast<const float4*>(xin + (size_t)src * 32);
    #pragma unroll
    for (int q = 0; q < 8; ++q) {
        float4 v = xp[q];
        xs[q * 4 + 0] = v.x; xs[q * 4 + 1] = v.y;
        xs[q * 4 + 2] = v.z; xs[q * 4 + 3] = v.w;
    }
    float* outp = agg + (size_t)dst * 256;
    #pragma unroll 1
    for (int d = 0; d < 8; ++d) {
        float t[64];
        const float4* b2p = reinterpret_cast<const float4*>(fc_b2 + d * 64);
        #pragma unroll
        for (int q = 0; q < 16; ++q) {
            float4 v = b2p[q];
            t[q * 4 + 0] = v.x; t[q * 4 + 1] = v.y;
            t[q * 4 + 2] = v.z; t[q * 4 + 3] = v.w;
        }
        for (int k = 0; k < HH; ++k) {
            float hv = hlds[k * EBS + threadIdx.x];
            const float4* wp = reinterpret_cast<const float4*>(fc_w2 + (size_t)k * 512 + d * 64);
            #pragma unroll
            for (int q = 0; q < 16; ++q) {
                float4 w = wp[q];
                t[q * 4 + 0] += hv * w.x;
                t[q * 4 + 1] += hv * w.y;
                t[q * 4 + 2] += hv * w.z;
                t[q * 4 + 3] += hv * w.w;
            }
        }
        #pragma unroll
        for (int c = 0; c < CC; ++c) {
            #pragma unroll
            for (int o = 0; o < 8; ++o) {
                float acc = 0.f;
                #pragma unroll
                for (int i = 0; i < 8; ++i) acc += xs[c * 8 + i] * t[i * 8 + o];
                atomicAdd(outp + c * 64 + d * 8 + o, acc);
            }
        }
    }
}

// ---------------------------------------------------------------------------
extern "C" void kernel_launch(void* const* d_in, const int* in_sizes, int n_in,
                              void* d_out, int out_size, void* d_ws, size_t ws_size,
                              hipStream_t stream)
{
    const float* node_input    = (const float*)d_in[0];
    const float* node_attr     = (const float*)d_in[1];
    const float* edge_features = (const float*)d_in[2];
    const float* W_sc          = (const float*)d_in[3];
    const float* W_lin1        = (const float*)d_in[4];
    const float* W_lin2        = (const float*)d_in[5];
    const float* fc_w1         = (const float*)d_in[6];
    const float* fc_b1         = (const float*)d_in[7];
    const float* fc_w2         = (const float*)d_in[8];
    const float* fc_b2         = (const float*)d_in[9];
    const int*   edge_src      = (const int*)d_in[10];
    const int*   edge_dst      = (const int*)d_in[11];

    const int N = in_sizes[1] / 16;
    const int E = in_sizes[10];

    char* ws = (char*)d_ws;
    size_t off = 0;
    auto take = [&](size_t bytes) { char* p = ws + off; off += (bytes + 15) & ~(size_t)15; return p; };
    float* xbuf            = (float*)take((size_t)N * 32 * sizeof(float));
    float* sbuf            = (float*)take((size_t)N * 32 * sizeof(float));
    float* w2n_ws          = (float*)take((size_t)N * 64 * sizeof(float));
    int*   counts          = (int*)take((size_t)N * sizeof(int));
    int*   offsets         = (int*)take((size_t)N * sizeof(int));
    int*   cursor          = (int*)take((size_t)N * sizeof(int));
    int2*  esrc            = (int2*)take((size_t)E * sizeof(int2));
    unsigned short* Bfrag  = (unsigned short*)take((size_t)17 * 4 * 64 * 8 * sizeof(unsigned short));
    unsigned short* Bfrag1 = (unsigned short*)take((size_t)4 * 64 * 8 * sizeof(unsigned short));
    unsigned short* Hbuf   = (unsigned short*)take((size_t)E * HH * sizeof(unsigned short));
    size_t fixed_off = off;
    unsigned short* Zbuf   = (unsigned short*)(ws + fixed_off);

    long long avail = (long long)ws_size - (long long)fixed_off;
    int npp = (avail > 0) ? (int)(avail / (4 * KEXT * 2)) : 0;   // bytes per node
    bool fast = (npp >= 64);

    float* out = (float*)d_out;

    // node prep: x, c_s*s, w2n (one wave per node, shuffle-based)
    k_nodeprep<<<(N + 3) / 4, 256, 0, stream>>>(
        node_input, node_attr, W_lin1, W_sc, W_lin2, xbuf, sbuf, w2n_ws, N);

    if (fast) {
        if (npp > N) npp = N;
        int passes = (N + npp - 1) / npp;
        npp = (N + passes - 1) / passes;

        // CSR over edge_dst ({e,src} gather)
        hipMemsetAsync(counts, 0, (size_t)N * sizeof(int), stream);
        k_hist<<<(E + 255) / 256, 256, 0, stream>>>(edge_dst, counts, E);
        k_scan<<<1, 1024, 0, stream>>>(counts, offsets, cursor, N);
        k_fill<<<(E + 255) / 256, 256, 0, stream>>>(edge_dst, edge_src, cursor, esrc, E);
        // pack W1 / W2+b2 into B-fragment order
        k_prep_bfrag1<<<(4 * 64 * 8 + 255) / 256, 256, 0, stream>>>(fc_w1, Bfrag1);
        k_prep_bfrag<<<(KEXT * 64 + 255) / 256, 256, 0, stream>>>(fc_w2, fc_b2, Bfrag);
        // radial layer-1 via MFMA, original order (coalesced, no LDS)
        k_hsilu<<<(E + 63) / 64, 256, 0, stream>>>(edge_features, Bfrag1, fc_b1, Hbuf, E);

        for (int p = 0; p < passes; ++p) {
            int n0 = p * npp;
            int nn = (n0 + npp <= N) ? npp : (N - n0);
            int M = nn * 4;
            k_zbuild<<<(nn + 3) / 4, 256, 0, stream>>>(
                Hbuf, esrc, offsets, counts, xbuf, Zbuf, n0, nn);
            k_gemm<<<(M + 63) / 64, 256, 0, stream>>>(Zbuf, Bfrag, out, n0 * 4, M);
        }
    } else {
        hipMemsetAsync(d_out, 0, (size_t)out_size * sizeof(float), stream);
        k_edge_atomic<<<(E + EBS - 1) / EBS, EBS, 0, stream>>>(
            edge_features, fc_w1, fc_b1, fc_w2, fc_b2, edge_src, edge_dst, xbuf, out, E);
    }

    // epilogue: per-node shuffle lin2 + self-connection (in place on out)
    k_node_out<<<(N + 3) / 4, 256, 0, stream>>>(sbuf, w2n_ws, out, N);
}

// Round 10
// 315.096 us; speedup vs baseline: 2.2340x; 1.2264x over previous
//
#include <hip/hip_runtime.h>
#include <math.h>

// Problem dims (fixed by reference)
#define CC 4
#define FE 32
#define HH 64
#define EBS 256
#define KEXT 544          // 512 + 32 (8 xbar cols + 24 zero pad), 17 K-steps of 32
#define ASTR 69           // uint4 per A-tile LDS row (552 shorts; pad kills bank conflicts)

typedef __attribute__((ext_vector_type(8))) short bf16x8;
typedef __attribute__((ext_vector_type(4))) float f32x4;

// bf16 round-to-nearest-even pack
__device__ inline unsigned short f2bf(float f) {
    unsigned u = __float_as_uint(f);
    u += 0x7fffu + ((u >> 16) & 1u);
    return (unsigned short)(u >> 16);
}
__device__ inline float bf2f(unsigned short b) {
    return __uint_as_float(((unsigned)b) << 16);
}

// ---------------------------------------------------------------------------
// Node prep (one wave per node, shuffle-based, low-VGPR)
// ---------------------------------------------------------------------------
__global__ __launch_bounds__(256) void k_nodeprep(
    const float* __restrict__ node_input, const float* __restrict__ node_attr,
    const float* __restrict__ W_lin1, const float* __restrict__ W_sc,
    const float* __restrict__ W_lin2,
    float* __restrict__ xbuf, float* __restrict__ sbuf,
    float* __restrict__ w2n_ws, int N)
{
    const float c_s = 0.3826834323650898f;
    const float c_x_scaled = 0.9238795325112867f * 0.35355339059327373f; // c_x/sqrt(8)
    int node = blockIdx.x * 4 + (threadIdx.x >> 6);
    int lane = threadIdx.x & 63;
    if (node >= N) return;

    float attr_own = (lane < 16) ? node_attr[(size_t)node * 16 + lane] : 0.f;
    float ni_own   = (lane < 32) ? node_input[(size_t)node * 32 + lane] : 0.f; // lane=c*8+i

    int iw = lane >> 3, jw = lane & 7;   // this lane's (i,j) / (o,p)
    float wb1 = 0.f, wbs = 0.f, w2n = 0.f;
    #pragma unroll
    for (int a = 0; a < 16; ++a) {
        float fa = __shfl(attr_own, a);
        int idx = (iw * 16 + a) * 8 + jw;
        wb1 += fa * W_lin1[idx];
        wbs += fa * W_sc[idx];
        w2n += fa * W_lin2[idx];
    }
    w2n_ws[(size_t)node * 64 + lane] = c_x_scaled * w2n;

    int c_ = (lane >> 3) & 3, jo = lane & 7;
    float xo = 0.f, so = 0.f;
    #pragma unroll
    for (int i = 0; i < 8; ++i) {
        float niv = __shfl(ni_own, c_ * 8 + i);
        xo += niv * __shfl(wb1, i * 8 + jo);
        so += niv * __shfl(wbs, i * 8 + jo);
    }
    if (lane < 32) {
        xbuf[(size_t)node * 32 + lane] = xo;
        sbuf[(size_t)node * 32 + lane] = c_s * so;
    }
}

// ---------------------------------------------------------------------------
// CSR build over edge_dst
// ---------------------------------------------------------------------------
__global__ __launch_bounds__(256) void k_hist(
    const int* __restrict__ edge_dst, int* __restrict__ counts, int E)
{
    int e = blockIdx.x * 256 + threadIdx.x;
    if (e < E) atomicAdd(&counts[edge_dst[e]], 1);
}

// single-block shfl-based scan (16 waves of 64)
__global__ __launch_bounds__(1024) void k_scan(
    const int* __restrict__ counts, int* __restrict__ offsets,
    int* __restrict__ cursor, int N)
{
    __shared__ int wsum[16];
    __shared__ int wpre[16];
    __shared__ int s_tot;
    __shared__ int s_carry;
    int tid = threadIdx.x, wid = tid >> 6, lane = tid & 63;
    if (tid == 0) s_carry = 0;
    __syncthreads();
    for (int base = 0; base < N; base += 1024) {
        int idx = base + tid;
        int v = (idx < N) ? counts[idx] : 0;
        int x = v;
        #pragma unroll
        for (int s = 1; s < 64; s <<= 1) {
            int y = __shfl_up(x, s);
            if (lane >= s) x += y;
        }
        if (lane == 63) wsum[wid] = x;
        __syncthreads();
        if (wid == 0) {
            int wv = (lane < 16) ? wsum[lane] : 0;
            int wx = wv;
            #pragma unroll
            for (int s = 1; s < 16; s <<= 1) {
                int y = __shfl_up(wx, s);
                if (lane >= s) wx += y;
            }
            if (lane < 16) wpre[lane] = wx - wv;
            if (lane == 15) s_tot = wx;
        }
        __syncthreads();
        if (idx < N) {
            int excl = s_carry + wpre[wid] + (x - v);
            offsets[idx] = excl;
            cursor[idx] = excl;
        }
        __syncthreads();
        if (tid == 0) s_carry += s_tot;
    }
}

// fill permutation: esrc[pos] = {edge id, src}
__global__ __launch_bounds__(256) void k_fill(
    const int* __restrict__ edge_dst, const int* __restrict__ edge_src,
    int* __restrict__ cursor, int2* __restrict__ esrc, int E)
{
    int e = blockIdx.x * 256 + threadIdx.x;
    if (e < E) {
        int pos = atomicAdd(&cursor[edge_dst[e]], 1);
        int2 v; v.x = e; v.y = edge_src[e];
        esrc[pos] = v;
    }
}

// ---------------------------------------------------------------------------
// Pack W2 (+ b2 as K-rows 512..519, zeros 520..543) into MFMA B-frag order.
// ---------------------------------------------------------------------------
__global__ __launch_bounds__(256) void k_prep_bfrag(
    const float* __restrict__ fc_w2, const float* __restrict__ fc_b2,
    unsigned short* __restrict__ Bfrag)
{
    int t = blockIdx.x * 256 + threadIdx.x;
    if (t >= KEXT * 64) return;
    int kappa = t >> 6, nu = t & 63;
    int d = nu >> 3, o = nu & 7;
    float val;
    if (kappa < 512)      val = fc_w2[(size_t)(kappa >> 3) * 512 + d * 64 + (kappa & 7) * 8 + o];
    else if (kappa < 520) val = fc_b2[d * 64 + (kappa & 7) * 8 + o];
    else                  val = 0.f;
    int kk = kappa >> 5;
    int lane = ((kappa >> 3) & 3) * 16 + (nu & 15);
    int ct = nu >> 4;
    int j = kappa & 7;
    Bfrag[(size_t)((kk * 4 + ct) * 64 + lane) * 8 + j] = f2bf(val);
}

// ---------------------------------------------------------------------------
// Pack W1 [32,64] into MFMA B-frag order (one K-step).
// ---------------------------------------------------------------------------
__global__ __launch_bounds__(256) void k_prep_bfrag1(
    const float* __restrict__ fc_w1, unsigned short* __restrict__ Bfrag1)
{
    int t = blockIdx.x * 256 + threadIdx.x;   // 2048 threads
    if (t >= 4 * 64 * 8) return;
    int j = t & 7, l = (t >> 3) & 63, ct = t >> 9;
    int k = (l >> 4) * 8 + j;
    int n = ct * 16 + (l & 15);
    Bfrag1[t] = f2bf(fc_w1[(size_t)k * HH + n]);
}

// ---------------------------------------------------------------------------
// H build via MFMA (original edge order, no LDS):
//   H[e, n] = silu(ef[e,:] @ W1[:,n] + b1[n]) as bf16
// ---------------------------------------------------------------------------
__global__ __launch_bounds__(256) void k_hsilu(
    const float* __restrict__ edge_features,
    const unsigned short* __restrict__ Bfrag1, const float* __restrict__ fc_b1,
    unsigned short* __restrict__ H, int E)
{
    int wid = threadIdx.x >> 6, lane = threadIdx.x & 63;
    int e0 = (blockIdx.x * 4 + wid) * 16;
    if (e0 >= E) return;

    bf16x8 b[4];
    #pragma unroll
    for (int ct = 0; ct < 4; ++ct) {
        uint4 bv = reinterpret_cast<const uint4*>(Bfrag1)[ct * 64 + lane];
        b[ct] = *reinterpret_cast<bf16x8*>(&bv);
    }
    float bias[4];
    #pragma unroll
    for (int ct = 0; ct < 4; ++ct) bias[ct] = fc_b1[ct * 16 + (lane & 15)];

    int row = e0 + (lane & 15);
    if (row >= E) row = E - 1;
    const float4* ap = reinterpret_cast<const float4*>(
        edge_features + (size_t)row * FE + (lane >> 4) * 8);
    float4 a0 = ap[0], a1 = ap[1];
    unsigned au[4];
    au[0] = (unsigned)f2bf(a0.x) | ((unsigned)f2bf(a0.y) << 16);
    au[1] = (unsigned)f2bf(a0.z) | ((unsigned)f2bf(a0.w) << 16);
    au[2] = (unsigned)f2bf(a1.x) | ((unsigned)f2bf(a1.y) << 16);
    au[3] = (unsigned)f2bf(a1.z) | ((unsigned)f2bf(a1.w) << 16);
    bf16x8 a = *reinterpret_cast<bf16x8*>(au);

    f32x4 acc[4];
    #pragma unroll
    for (int ct = 0; ct < 4; ++ct) {
        acc[ct] = (f32x4){0.f, 0.f, 0.f, 0.f};
        acc[ct] = __builtin_amdgcn_mfma_f32_16x16x32_bf16(a, b[ct], acc[ct], 0, 0, 0);
    }

    #pragma unroll
    for (int ct = 0; ct < 4; ++ct) {
        #pragma unroll
        for (int v = 0; v < 4; ++v) {
            int r = e0 + (lane >> 4) * 4 + v;
            if (r < E) {
                float x = acc[ct][v] + bias[ct];
                float s = x / (1.f + __expf(-x));
                H[(size_t)r * HH + ct * 16 + (lane & 15)] = f2bf(s);
            }
        }
    }
}

// ---------------------------------------------------------------------------
// FUSED zbuild + GEMM. Block = 4 waves = 4 nodes = one 16-row MFMA tile.
// Phase 1 (per wave): accumulate z[c][i] over the node's edges (registers).
// Phase 2: pack 4 rows (+xbar, +zero pad) into LDS A-tile [16][ASTR uint4].
// Phase 3: wave w = column tile ct=w: 17 MFMA (16 W2 K-steps + bias K-step),
//          B fragments loaded from L2-hot Bfrag after the edge loop.
// Stores agg rows directly to out. No Z buffer, no passes.
// ---------------------------------------------------------------------------
__global__ __launch_bounds__(256) void k_zgemm(
    const unsigned short* __restrict__ H, const int2* __restrict__ esrc,
    const int* __restrict__ offsets, const int* __restrict__ counts,
    const float* __restrict__ xin, const unsigned short* __restrict__ Bfrag,
    float* __restrict__ out, int N)
{
    __shared__ uint4 alds[16 * ASTR];   // 17664 B
    int wid = threadIdx.x >> 6, lane = threadIdx.x & 63;
    int node = blockIdx.x * 4 + wid;
    bool valid = (node < N);

    // ---- Phase 1: edge accumulation (lane k owns h[e,k]) ----
    float z[CC][8];
    #pragma unroll
    for (int c = 0; c < CC; ++c)
        #pragma unroll
        for (int i = 0; i < 8; ++i) z[c][i] = 0.f;
    float xsown = 0.f;

    int off = 0, cnt = 0;
    if (valid) { off = offsets[node]; cnt = counts[node]; }
    for (int base = 0; base < cnt; base += 64) {
        int m = (cnt - base < 64) ? (cnt - base) : 64;
        int2 ej = (lane < m) ? esrc[off + base + lane] : make_int2(0, 0);
        #pragma unroll 2
        for (int j = 0; j < m; ++j) {
            int e   = __shfl(ej.x, j);
            int src = __shfl(ej.y, j);
            float hk = bf2f(H[(size_t)e * HH + lane]);
            const float4* xp = reinterpret_cast<const float4*>(xin + (size_t)src * 32);
            float xs[32];
            #pragma unroll
            for (int q = 0; q < 8; ++q) {
                float4 v = xp[q];
                xs[q * 4 + 0] = v.x; xs[q * 4 + 1] = v.y;
                xs[q * 4 + 2] = v.z; xs[q * 4 + 3] = v.w;
            }
            #pragma unroll
            for (int c = 0; c < CC; ++c)
                #pragma unroll
                for (int i = 0; i < 8; ++i)
                    z[c][i] += hk * xs[c * 8 + i];
            xsown += xin[(size_t)src * 32 + (lane & 31)];
        }
    }

    // ---- Phase 2: pack this node's 4 rows into the LDS A-tile ----
    #pragma unroll
    for (int c = 0; c < CC; ++c) {
        uint4 pk;
        pk.x = (unsigned)f2bf(z[c][0]) | ((unsigned)f2bf(z[c][1]) << 16);
        pk.y = (unsigned)f2bf(z[c][2]) | ((unsigned)f2bf(z[c][3]) << 16);
        pk.z = (unsigned)f2bf(z[c][4]) | ((unsigned)f2bf(z[c][5]) << 16);
        pk.w = (unsigned)f2bf(z[c][6]) | ((unsigned)f2bf(z[c][7]) << 16);
        alds[(wid * 4 + c) * ASTR + lane] = pk;
    }
    // xbar cols 512..519 (row c gets xsown of lanes c*8..c*8+7); zeros 520..543
    float xb[8];
    #pragma unroll
    for (int i = 0; i < 8; ++i) xb[i] = __shfl(xsown, (lane & 3) * 8 + i);
    int r4 = wid * 4;
    if (lane < 4) {
        uint4 pk;
        pk.x = (unsigned)f2bf(xb[0]) | ((unsigned)f2bf(xb[1]) << 16);
        pk.y = (unsigned)f2bf(xb[2]) | ((unsigned)f2bf(xb[3]) << 16);
        pk.z = (unsigned)f2bf(xb[4]) | ((unsigned)f2bf(xb[5]) << 16);
        pk.w = (unsigned)f2bf(xb[6]) | ((unsigned)f2bf(xb[7]) << 16);
        alds[(r4 + lane) * ASTR + 64] = pk;
    } else if (lane < 16) {
        int j = lane - 4;   // 12 zero uint4s: rows 0..3 x slots 65..67
        uint4 zz; zz.x = 0u; zz.y = 0u; zz.z = 0u; zz.w = 0u;
        alds[(r4 + (j & 3)) * ASTR + 65 + (j >> 2)] = zz;
    }

    // ---- B fragments for ct = wid (loaded post-loop: low edge-loop VGPR) ----
    bf16x8 bfr[17];
    #pragma unroll
    for (int kk = 0; kk < 16; ++kk) {
        uint4 bv = reinterpret_cast<const uint4*>(Bfrag)[(kk * 4 + wid) * 64 + lane];
        bfr[kk] = *reinterpret_cast<bf16x8*>(&bv);
    }
    {
        uint4 bv = reinterpret_cast<const uint4*>(Bfrag)[(64 + wid) * 64 + lane];
        bfr[16] = *reinterpret_cast<bf16x8*>(&bv);
    }

    __syncthreads();

    // ---- Phase 3: GEMM, wave = ct ----
    f32x4 acc = (f32x4){0.f, 0.f, 0.f, 0.f};
    #pragma unroll
    for (int kk = 0; kk < 16; ++kk) {
        uint4 av = alds[(lane & 15) * ASTR + kk * 4 + (lane >> 4)];
        bf16x8 a = *reinterpret_cast<bf16x8*>(&av);
        acc = __builtin_amdgcn_mfma_f32_16x16x32_bf16(a, bfr[kk], acc, 0, 0, 0);
    }
    {   // bias K-step (cols 512..543)
        uint4 av = alds[(lane & 15) * ASTR + 64 + (lane >> 4)];
        bf16x8 a = *reinterpret_cast<bf16x8*>(&av);
        acc = __builtin_amdgcn_mfma_f32_16x16x32_bf16(a, bfr[16], acc, 0, 0, 0);
    }

    int rbase = blockIdx.x * 16;
    int M = N * 4;
    #pragma unroll
    for (int v = 0; v < 4; ++v) {
        int r = rbase + (lane >> 4) * 4 + v;
        if (r < M)
            out[(size_t)r * 64 + wid * 16 + (lane & 15)] = acc[v];
    }
}

// ---------------------------------------------------------------------------
// Kernel C: one wave per node, pure-register shuffle epilogue.
// ---------------------------------------------------------------------------
__global__ __launch_bounds__(256) void k_node_out(
    const float* __restrict__ sbuf, const float* __restrict__ w2n_ws,
    float* __restrict__ out, int N)
{
    int node = blockIdx.x * 4 + (threadIdx.x >> 6);
    int lane = threadIdx.x & 63;
    if (node >= N) return;
    int d = lane >> 3, p = lane & 7;

    float w2 = w2n_ws[(size_t)node * 64 + lane];
    float s_own = sbuf[(size_t)node * 32 + (lane & 31)];

    float w2sh[8];
    #pragma unroll
    for (int o = 0; o < 8; ++o) w2sh[o] = __shfl(w2, o * 8 + p);

    float* rowp = out + (size_t)node * 256;
    #pragma unroll
    for (int c = 0; c < CC; ++c) {
        float a_own = rowp[c * 64 + lane];
        float res = 0.f;
        #pragma unroll
        for (int o = 0; o < 8; ++o)
            res += __shfl(a_own, d * 8 + o) * w2sh[o];
        float sval = __shfl(s_own, c * 8 + p);
        rowp[c * 64 + lane] = sval + res;
    }
}

// ---------------------------------------------------------------------------
// Fallback edge kernel (global atomics) — only if ws too small.
// ---------------------------------------------------------------------------
__global__ __launch_bounds__(EBS) void k_edge_atomic(
    const float* __restrict__ edge_features,
    const float* __restrict__ fc_w1, const float* __restrict__ fc_b1,
    const float* __restrict__ fc_w2, const float* __restrict__ fc_b2,
    const int* __restrict__ edge_src, const int* __restrict__ edge_dst,
    const float* __restrict__ xin, float* __restrict__ agg, int E)
{
    __shared__ float hlds[HH * EBS];
    int e = blockIdx.x * EBS + threadIdx.x;
    if (e >= E) return;
    float h[HH];
    #pragma unroll
    for (int k = 0; k < HH; ++k) h[k] = fc_b1[k];
    const float4* efp = reinterpret_cast<const float4*>(edge_features + (size_t)e * FE);
    #pragma unroll
    for (int fq = 0; fq < FE / 4; ++fq) {
        float4 efv = efp[fq];
        float ev[4] = {efv.x, efv.y, efv.z, efv.w};
        #pragma unroll
        for (int fs = 0; fs < 4; ++fs) {
            float evv = ev[fs];
            const float4* w1p = reinterpret_cast<const float4*>(fc_w1 + (fq * 4 + fs) * HH);
            #pragma unroll
            for (int q = 0; q < HH / 4; ++q) {
                float4 w = w1p[q];
                h[q * 4 + 0] += evv * w.x;
                h[q * 4 + 1] += evv * w.y;
                h[q * 4 + 2] += evv * w.z;
                h[q * 4 + 3] += evv * w.w;
            }
        }
    }
    #pragma unroll
    for (int k = 0; k < HH; ++k) {
        float v = h[k];
        hlds[k * EBS + threadIdx.x] = v / (1.f + __expf(-v));
    }
    int src = edge_src[e], dst = edge_dst[e];
    float xs[32];
    const float4* xp = reinterpret_cast<const float4*>(xin + (size_t)src * 32);
    #pragma unroll
    for (int q = 0; q < 8; ++q) {
        float4 v = xp[q];
        xs[q * 4 + 0] = v.x; xs[q * 4 + 1] = v.y;
        xs[q * 4 + 2] = v.z; xs[q * 4 + 3] = v.w;
    }
    float* outp = agg + (size_t)dst * 256;
    #pragma unroll 1
    for (int d = 0; d < 8; ++d) {
        float t[64];
        const float4* b2p = reinterpret_cast<const float4*>(fc_b2 + d * 64);
        #pragma unroll
        for (int q = 0; q < 16; ++q) {
            float4 v = b2p[q];
            t[q * 4 + 0] = v.x; t[q * 4 + 1] = v.y;
            t[q * 4 + 2] = v.z; t[q * 4 + 3] = v.w;
        }
        for (int k = 0; k < HH; ++k) {
            float hv = hlds[k * EBS + threadIdx.x];
            const float4* wp = reinterpret_cast<const float4*>(fc_w2 + (size_t)k * 512 + d * 64);
            #pragma unroll
            for (int q = 0; q < 16; ++q) {
                float4 w = wp[q];
                t[q * 4 + 0] += hv * w.x;
                t[q * 4 + 1] += hv * w.y;
                t[q * 4 + 2] += hv * w.z;
                t[q * 4 + 3] += hv * w.w;
            }
        }
        #pragma unroll
        for (int c = 0; c < CC; ++c) {
            #pragma unroll
            for (int o = 0; o < 8; ++o) {
                float acc = 0.f;
                #pragma unroll
                for (int i = 0; i < 8; ++i) acc += xs[c * 8 + i] * t[i * 8 + o];
                atomicAdd(outp + c * 64 + d * 8 + o, acc);
            }
        }
    }
}

// ---------------------------------------------------------------------------
extern "C" void kernel_launch(void* const* d_in, const int* in_sizes, int n_in,
                              void* d_out, int out_size, void* d_ws, size_t ws_size,
                              hipStream_t stream)
{
    const float* node_input    = (const float*)d_in[0];
    const float* node_attr     = (const float*)d_in[1];
    const float* edge_features = (const float*)d_in[2];
    const float* W_sc          = (const float*)d_in[3];
    const float* W_lin1        = (const float*)d_in[4];
    const float* W_lin2        = (const float*)d_in[5];
    const float* fc_w1         = (const float*)d_in[6];
    const float* fc_b1         = (const float*)d_in[7];
    const float* fc_w2         = (const float*)d_in[8];
    const float* fc_b2         = (const float*)d_in[9];
    const int*   edge_src      = (const int*)d_in[10];
    const int*   edge_dst      = (const int*)d_in[11];

    const int N = in_sizes[1] / 16;
    const int E = in_sizes[10];

    char* ws = (char*)d_ws;
    size_t off = 0;
    auto take = [&](size_t bytes) { char* p = ws + off; off += (bytes + 15) & ~(size_t)15; return p; };
    float* xbuf            = (float*)take((size_t)N * 32 * sizeof(float));
    float* sbuf            = (float*)take((size_t)N * 32 * sizeof(float));
    float* w2n_ws          = (float*)take((size_t)N * 64 * sizeof(float));
    int*   counts          = (int*)take((size_t)N * sizeof(int));
    int*   offsets         = (int*)take((size_t)N * sizeof(int));
    int*   cursor          = (int*)take((size_t)N * sizeof(int));
    int2*  esrc            = (int2*)take((size_t)E * sizeof(int2));
    unsigned short* Bfrag  = (unsigned short*)take((size_t)17 * 4 * 64 * 8 * sizeof(unsigned short));
    unsigned short* Bfrag1 = (unsigned short*)take((size_t)4 * 64 * 8 * sizeof(unsigned short));
    unsigned short* Hbuf   = (unsigned short*)take((size_t)E * HH * sizeof(unsigned short));
    bool fast = (off <= ws_size);

    float* out = (float*)d_out;

    // node prep: x, c_s*s, w2n (one wave per node, shuffle-based)
    k_nodeprep<<<(N + 3) / 4, 256, 0, stream>>>(
        node_input, node_attr, W_lin1, W_sc, W_lin2, xbuf, sbuf, w2n_ws, N);

    if (fast) {
        // CSR over edge_dst ({e,src} gather)
        hipMemsetAsync(counts, 0, (size_t)N * sizeof(int), stream);
        k_hist<<<(E + 255) / 256, 256, 0, stream>>>(edge_dst, counts, E);
        k_scan<<<1, 1024, 0, stream>>>(counts, offsets, cursor, N);
        k_fill<<<(E + 255) / 256, 256, 0, stream>>>(edge_dst, edge_src, cursor, esrc, E);
        // pack W1 / W2+b2 into B-fragment order
        k_prep_bfrag1<<<(4 * 64 * 8 + 255) / 256, 256, 0, stream>>>(fc_w1, Bfrag1);
        k_prep_bfrag<<<(KEXT * 64 + 255) / 256, 256, 0, stream>>>(fc_w2, fc_b2, Bfrag);
        // radial layer-1 via MFMA, original order (coalesced, no LDS)
        k_hsilu<<<(E + 63) / 64, 256, 0, stream>>>(edge_features, Bfrag1, fc_b1, Hbuf, E);
        // fused aggregation + GEMM (no Z buffer, single launch)
        k_zgemm<<<(N + 3) / 4, 256, 0, stream>>>(
            Hbuf, esrc, offsets, counts, xbuf, Bfrag, out, N);
    } else {
        hipMemsetAsync(d_out, 0, (size_t)out_size * sizeof(float), stream);
        k_edge_atomic<<<(E + EBS - 1) / EBS, EBS, 0, stream>>>(
            edge_features, fc_w1, fc_b1, fc_w2, fc_b2, edge_src, edge_dst, xbuf, out, E);
    }

    // epilogue: per-node shuffle lin2 + self-connection (in place on out)
    k_node_out<<<(N + 3) / 4, 256, 0, stream>>>(sbuf, w2n_ws, out, N);
}